// Round 16
// baseline (3591.909 us; speedup 1.0000x reference)
//
#include <hip/hip_runtime.h>
#include <math.h>

#define N_NODES 100000
#define H 200
#define R2 500
#define T_STEPS 3
#define E_EDGES 300000
#define R2E 400000
#define SE_EDGES 4000
#define SR 8
#define S2E 8000
#define SLOPE 0.22916666666666666f
#define NB 64            // partition blocks per timestep for r_seg
#define RCHUNK ((R2E + NB - 1) / NB)
#define NCH 128          // chunks per timestep for entity CSR scan
#define CHSZ ((N_NODES + NCH - 1) / NCH)   // 782
#define SPT  ((CHSZ + 255) / 256)          // 4 elems per thread in scan phases

typedef unsigned short u16;
typedef unsigned int u32;
typedef __bf16 bf8 __attribute__((ext_vector_type(8)));
typedef float f32x4 __attribute__((ext_vector_type(4)));

static __device__ __forceinline__ float fsig(float x) { return 1.f / (1.f + __expf(-x)); }
static __device__ __forceinline__ float ftanh(float x) {
    float e = __expf(-2.f * fabsf(x));
    float t = (1.f - e) / (1.f + e);
    return (x >= 0.f) ? t : -t;
}
static __device__ __forceinline__ float bf2f(u32 lo16) {
    u32 v = lo16 << 16; float f; __builtin_memcpy(&f, &v, 4); return f;
}
static __device__ __forceinline__ u16 f2bf(float a) {
    __bf16 x = (__bf16)a; u16 u; __builtin_memcpy(&u, &x, 2); return u;
}
static __device__ __forceinline__ u32 pk2(float a, float b) {
    return (u32)f2bf(a) | ((u32)f2bf(b) << 16);
}
// bijective XCD swizzle (m204)
static __device__ __forceinline__ int xcd_swz(int b, int nwg) {
    int q = nwg >> 3, r = nwg & 7;
    int xcd = b & 7, u = b >> 3;
    int start = xcd * q + (xcd < r ? xcd : r);
    return start + u;
}

// ---------------- l2 normalize rows fp32 (+optional bf16 mirror); src may alias dst ----------------
__global__ __launch_bounds__(256) void l2norm_k(const float* __restrict__ src, float* __restrict__ dst,
                                                u16* __restrict__ mir, int rows) {
    int wave = threadIdx.x >> 6, lane = threadIdx.x & 63;
    int r = blockIdx.x * 4 + wave;
    if (r >= rows) return;
    float4 v = make_float4(0.f, 0.f, 0.f, 0.f);
    if (lane < 50) v = *(const float4*)(src + (size_t)r * H + lane * 4);
    float s = v.x * v.x + v.y * v.y + v.z * v.z + v.w * v.w;
    for (int o = 32; o > 0; o >>= 1) s += __shfl_down(s, o);
    float rn = 1.f / fmaxf(sqrtf(__shfl(s, 0)), 1e-12f);
    if (lane < 50) {
        float4 o4 = make_float4(v.x * rn, v.y * rn, v.z * rn, v.w * rn);
        *(float4*)(dst + (size_t)r * H + lane * 4) = o4;
        if (mir) {
            uint2 u; u.x = pk2(o4.x, o4.y); u.y = pk2(o4.z, o4.w);
            *(uint2*)(mir + (size_t)r * H + lane * 4) = u;
        }
    }
}

// ---------------- l2 normalize bf16 rows in place ----------------
__global__ __launch_bounds__(256) void l2norm_b_k(u16* __restrict__ buf, int rows) {
    int wave = threadIdx.x >> 6, lane = threadIdx.x & 63;
    int r = blockIdx.x * 4 + wave;
    if (r >= rows) return;
    uint2 u = make_uint2(0, 0);
    if (lane < 50) u = *(const uint2*)(buf + (size_t)r * H + lane * 4);
    float x0 = bf2f(u.x & 0xffff), x1 = bf2f(u.x >> 16);
    float x2 = bf2f(u.y & 0xffff), x3 = bf2f(u.y >> 16);
    float s = x0 * x0 + x1 * x1 + x2 * x2 + x3 * x3;
    for (int o = 32; o > 0; o >>= 1) s += __shfl_down(s, o);
    float rn = 1.f / fmaxf(sqrtf(__shfl(s, 0)), 1e-12f);
    if (lane < 50) {
        uint2 o2; o2.x = pk2(x0 * rn, x1 * rn); o2.y = pk2(x2 * rn, x3 * rn);
        *(uint2*)(buf + (size_t)r * H + lane * 4) = o2;
    }
}

// ---------------- l2 normalize bf16 src -> fp32 dst + bf16 mirror ----------------
__global__ __launch_bounds__(256) void l2norm_bb_k(const u16* __restrict__ src, float* __restrict__ dst,
                                                   u16* __restrict__ mir, int rows) {
    int wave = threadIdx.x >> 6, lane = threadIdx.x & 63;
    int r = blockIdx.x * 4 + wave;
    if (r >= rows) return;
    uint2 u = make_uint2(0, 0);
    if (lane < 50) u = *(const uint2*)(src + (size_t)r * H + lane * 4);
    float x0 = bf2f(u.x & 0xffff), x1 = bf2f(u.x >> 16);
    float x2 = bf2f(u.y & 0xffff), x3 = bf2f(u.y >> 16);
    float s = x0 * x0 + x1 * x1 + x2 * x2 + x3 * x3;
    for (int o = 32; o > 0; o >>= 1) s += __shfl_down(s, o);
    float rn = 1.f / fmaxf(sqrtf(__shfl(s, 0)), 1e-12f);
    if (lane < 50) {
        float4 o4 = make_float4(x0 * rn, x1 * rn, x2 * rn, x3 * rn);
        *(float4*)(dst + (size_t)r * H + lane * 4) = o4;
        uint2 o2; o2.x = pk2(o4.x, o4.y); o2.y = pk2(o4.z, o4.w);
        *(uint2*)(mir + (size_t)r * H + lane * 4) = o2;
    }
}

// ---------------- weight converts ----------------
__global__ void wconv4_k(const float* __restrict__ W0, const float* __restrict__ W1,
                         const float* __restrict__ W2, const float* __restrict__ W3,
                         u16* __restrict__ o) {
    int m = blockIdx.y;
    const float* W = (m == 0) ? W0 : (m == 1) ? W1 : (m == 2) ? W2 : W3;
    int i = blockIdx.x * 256 + threadIdx.x;
    if (i < 40000) { int n = i / 200, k = i - n * 200; o[m * 40000 + i] = f2bf(W[k * 200 + n]); }
}
__global__ void wconv2_k(const float* __restrict__ Wa, const float* __restrict__ Wb, u16* __restrict__ o) {
    int i = blockIdx.x * 256 + threadIdx.x;
    if (i < 240000) o[i] = f2bf(i < 120000 ? Wa[i] : Wb[i - 120000]);
}

// ---------------- batched counting over 3 timesteps ----------------
__global__ void cnt3_k(const int* __restrict__ d, int total, int per_t, int stride, int* __restrict__ cnt) {
    int i = blockIdx.x * 256 + threadIdx.x;
    if (i < total) { int t = i / per_t; atomicAdd(&cnt[t * stride + d[i]], 1); }
}

// ---------------- r_seg partition: per-block histogram + totals ----------------
__global__ __launch_bounds__(256) void hist3_k(const int* __restrict__ seg,
                                               int* __restrict__ hist, int* __restrict__ cnt) {
    __shared__ int lc[R2];
    int t = blockIdx.x / NB;
    int pb = blockIdx.x - t * NB;
    const int* s = seg + (size_t)t * R2E;
    for (int i = threadIdx.x; i < R2; i += 256) lc[i] = 0;
    __syncthreads();
    int beg = pb * RCHUNK;
    int end = beg + RCHUNK; if (end > R2E) end = R2E;
    for (int i = beg + threadIdx.x; i < end; i += 256) atomicAdd(&lc[s[i]], 1);
    __syncthreads();
    int* hrow = hist + (size_t)(t * NB + pb) * R2;
    int* c = cnt + (size_t)t * R2;
    for (int i = threadIdx.x; i < R2; i += 256) {
        hrow[i] = lc[i];
        if (lc[i]) atomicAdd(&c[i], lc[i]);
    }
}

// ---------------- small batched CSR scan (single block per t; for nseg<=1000) ----------------
__global__ __launch_bounds__(1024) void scan3_k(const int* __restrict__ cntA, int* __restrict__ offA,
                                                int* __restrict__ curA, int n) {
    const int b = blockIdx.x;
    const int* cnt = cntA + (size_t)b * n;
    int* off = offA + (size_t)b * (n + 1);
    int* cur = curA + (size_t)b * n;
    __shared__ int part[1024];
    int tid = threadIdx.x;
    int per = (n + 1023) / 1024;
    int s0 = tid * per;
    int e0 = s0 + per; if (e0 > n) e0 = n;
    int sum = 0;
    for (int i = s0; i < e0; ++i) sum += cnt[i];
    part[tid] = sum;
    __syncthreads();
    for (int d = 1; d < 1024; d <<= 1) {
        int v = (tid >= d) ? part[tid - d] : 0;
        __syncthreads();
        part[tid] += v;
        __syncthreads();
    }
    int excl = (tid == 0) ? 0 : part[tid - 1];
    for (int i = s0; i < e0; ++i) { off[i] = excl; cur[i] = excl; excl += cnt[i]; }
    if (tid == 1023) off[n] = excl;
}

// ---------------- multi-block entity CSR scan: phase A (chunk sums) ----------------
__global__ __launch_bounds__(256) void scanA_k(const int* __restrict__ cntA, int* __restrict__ bsum, int n) {
    int b = blockIdx.x;
    int t = b / NCH, ch = b - t * NCH;
    const int* cnt = cntA + (size_t)t * n;
    int base = ch * CHSZ;
    int cend = base + CHSZ; if (cend > n) cend = n;
    int s0 = base + threadIdx.x * SPT;
    int e0 = s0 + SPT; if (e0 > cend) e0 = cend;
    int sum = 0;
    for (int i = s0; i < e0 && i < cend; ++i) sum += cnt[i];
    __shared__ int red[256];
    red[threadIdx.x] = (s0 < cend) ? sum : 0;
    __syncthreads();
    for (int o = 128; o > 0; o >>= 1) {
        if (threadIdx.x < o) red[threadIdx.x] += red[threadIdx.x + o];
        __syncthreads();
    }
    if (threadIdx.x == 0) bsum[t * NCH + ch] = red[0];
}

// ---------------- phase B: exclusive scan of chunk sums per timestep (+ write off[n]) ----------------
__global__ __launch_bounds__(128) void scanB_k(const int* __restrict__ bsum, int* __restrict__ boff,
                                               int* __restrict__ offA, int n) {
    int t = blockIdx.x;
    int tid = threadIdx.x;  // 0..127
    __shared__ int part[128];
    int v = bsum[t * NCH + tid];
    part[tid] = v;
    __syncthreads();
    for (int d = 1; d < 128; d <<= 1) {
        int u = (tid >= d) ? part[tid - d] : 0;
        __syncthreads();
        part[tid] += u;
        __syncthreads();
    }
    boff[t * NCH + tid] = part[tid] - v;   // exclusive
    if (tid == 127) offA[(size_t)t * (n + 1) + n] = part[127];
}

// ---------------- phase C: per-chunk scan + carry, write off/cur ----------------
__global__ __launch_bounds__(256) void scanC_k(const int* __restrict__ cntA, const int* __restrict__ boff,
                                               int* __restrict__ offA, int* __restrict__ curA, int n) {
    int b = blockIdx.x;
    int t = b / NCH, ch = b - t * NCH;
    const int* cnt = cntA + (size_t)t * n;
    int* off = offA + (size_t)t * (n + 1);
    int* cur = curA + (size_t)t * n;
    int base = ch * CHSZ;
    int cend = base + CHSZ; if (cend > n) cend = n;
    int s0 = base + threadIdx.x * SPT;
    int e0 = s0 + SPT; if (e0 > cend) e0 = cend;
    int sum = 0;
    for (int i = s0; i < e0 && i < cend; ++i) sum += cnt[i];
    __shared__ int part[256];
    int my = (s0 < cend) ? sum : 0;
    part[threadIdx.x] = my;
    __syncthreads();
    for (int d = 1; d < 256; d <<= 1) {
        int u = (threadIdx.x >= d) ? part[threadIdx.x - d] : 0;
        __syncthreads();
        part[threadIdx.x] += u;
        __syncthreads();
    }
    int excl = boff[t * NCH + ch] + part[threadIdx.x] - my;
    for (int i = s0; i < e0 && i < cend; ++i) {
        off[i] = excl; cur[i] = excl; excl += cnt[i];
    }
}

// ---------------- r_seg partition: per-(block,seg) offsets via wave scan ----------------
__global__ __launch_bounds__(64) void offs3_k(const int* __restrict__ hist, const int* __restrict__ csr,
                                              int* __restrict__ offb) {
    int b = blockIdx.x;            // 0..3*R2-1
    int t = b / R2, s = b - t * R2;
    int lane = threadIdx.x;        // 0..63 = block index
    int v = hist[(size_t)(t * NB + lane) * R2 + s];
    int pre = v;
    for (int o = 1; o < 64; o <<= 1) {
        int u = __shfl_up(pre, o);
        if (lane >= o) pre += u;
    }
    int base = csr[(size_t)t * (R2 + 1) + s];
    offb[(size_t)(t * NB + lane) * R2 + s] = base + pre - v;
}

// ---------------- r_seg partition: scatter with LDS counters ----------------
__global__ __launch_bounds__(256) void part3_k(const int* __restrict__ seg, const int* __restrict__ val,
                                               const int* __restrict__ offb, int* __restrict__ outp) {
    __shared__ int cur[R2];
    int t = blockIdx.x / NB;
    int pb = blockIdx.x - t * NB;
    const int* s = seg + (size_t)t * R2E;
    const int* v = val + (size_t)t * R2E;
    const int* ob = offb + (size_t)(t * NB + pb) * R2;
    int* o = outp + (size_t)t * R2E;
    for (int i = threadIdx.x; i < R2; i += 256) cur[i] = ob[i];
    __syncthreads();
    int beg = pb * RCHUNK;
    int end = beg + RCHUNK; if (end > R2E) end = R2E;
    for (int i = beg + threadIdx.x; i < end; i += 256) {
        int p = atomicAdd(&cur[s[i]], 1);
        o[p] = v[i];
    }
}

// ---------------- batched scatters (entity + super CSR; low contention) ----------------
__global__ void scatter3_k(const int* __restrict__ dst, const int* __restrict__ src,
                           const int* __restrict__ et, int* __restrict__ cur,
                           int* __restrict__ psrc, int* __restrict__ pet,
                           int per_t, int stride, int total) {
    int i = blockIdx.x * 256 + threadIdx.x;
    if (i < total) {
        int t = i / per_t;
        int p = atomicAdd(&cur[t * stride + dst[i]], 1);
        psrc[(size_t)t * per_t + p] = src[i];
        pet[(size_t)t * per_t + p] = et[i];
    }
}

// ---------------- block-aggregated zero-indeg list (1 atomic per block) ----------------
__global__ __launch_bounds__(256) void zlist3b_k(const int* __restrict__ cnt, int* __restrict__ zl,
                                                 int* __restrict__ nz, int n, int bpt) {
    int t = blockIdx.x / bpt;
    int pb = blockIdx.x - t * bpt;
    int i = pb * 256 + threadIdx.x;
    bool z = (i < n) && (cnt[(size_t)t * n + i] == 0);
    unsigned long long mask = __ballot(z);
    int wave = threadIdx.x >> 6, lane = threadIdx.x & 63;
    __shared__ int wbase[4];
    __shared__ int bbase;
    if (lane == 0) wbase[wave] = __popcll(mask);
    __syncthreads();
    if (threadIdx.x == 0) {
        int s0 = wbase[0], s1 = wbase[1], s2 = wbase[2], s3 = wbase[3];
        int tot = s0 + s1 + s2 + s3;
        bbase = tot ? atomicAdd(&nz[t], tot) : 0;
        wbase[0] = 0; wbase[1] = s0; wbase[2] = s0 + s1; wbase[3] = s0 + s1 + s2;
    }
    __syncthreads();
    if (z) {
        int off = bbase + wbase[wave] + __popcll(mask & ((1ull << lane) - 1ull));
        zl[(size_t)t * n + off] = i;
    }
}

// ---------------- fused SR segment mean: 8 blocks, scan + gather + count + divide ----------------
__global__ __launch_bounds__(256) void seg_mean_sr_k(const float* __restrict__ h,
                                                     const int* __restrict__ idx,
                                                     const int* __restrict__ seg,
                                                     float* __restrict__ outp) {
    int r = blockIdx.x;             // 0..SR-1
    int wv = threadIdx.x >> 6, lane = threadIdx.x & 63;
    __shared__ float acc[4][200];
    __shared__ int cntl[4];
    for (int i = threadIdx.x; i < 800; i += 256) ((float*)acc)[i] = 0.f;
    __syncthreads();
    int cnt = 0;
    for (int i = wv; i < S2E; i += 4) {
        if (seg[i] == r) {
            const float* row = h + (size_t)idx[i] * H;
            acc[wv][lane] += row[lane];
            acc[wv][lane + 64] += row[lane + 64];
            int c3 = lane + 128;
            acc[wv][c3] += row[c3];
            int c4 = lane + 192;
            if (c4 < 200) acc[wv][c4] += row[c4];
            ++cnt;
        }
    }
    if (lane == 0) cntl[wv] = cnt;
    __syncthreads();
    int t = threadIdx.x;
    if (t < 200) {
        float s = acc[0][t] + acc[1][t] + acc[2][t] + acc[3][t];
        int c = cntl[0] + cntl[1] + cntl[2] + cntl[3];
        outp[(size_t)r * H + t] = s / (float)(c > 0 ? c : 1);
    }
}

// ---------------- seg-mean partials: 4 blocks per segment, disjoint buffers (no atomics) ----------------
__global__ __launch_bounds__(256) void seg_mean_part_k(const u16* __restrict__ h,
                                                       const int* __restrict__ per,
                                                       const int* __restrict__ off,
                                                       float* __restrict__ xpart, int nseg) {
    int r = blockIdx.x >> 2;
    int p = blockIdx.x & 3;
    if (r >= nseg) return;
    int wv = threadIdx.x >> 6, lane = threadIdx.x & 63;
    int beg = off[r], end = off[r + 1];
    float a0 = 0.f, a1 = 0.f, a2 = 0.f, a3 = 0.f;
    for (int i = beg + p * 4 + wv; i < end; i += 16) {
        int e = per[i];
        if (lane < 50) {
            uint2 u = ((const uint2*)(h + (size_t)e * H))[lane];
            a0 += bf2f(u.x & 0xffff); a1 += bf2f(u.x >> 16);
            a2 += bf2f(u.y & 0xffff); a3 += bf2f(u.y >> 16);
        }
    }
    __shared__ float red[4][200];
    if (lane < 50) *(float4*)(&red[wv][lane * 4]) = make_float4(a0, a1, a2, a3);
    __syncthreads();
    int t = threadIdx.x;
    if (t < 200) {
        float s = red[0][t] + red[1][t] + red[2][t] + red[3][t];
        xpart[((size_t)p * nseg + r) * H + t] = s;
    }
}
__global__ void seg_fin_k(const float* __restrict__ xpart, const int* __restrict__ off,
                          float* __restrict__ acc, int nseg) {
    int i = blockIdx.x * 256 + threadIdx.x;
    if (i < nseg * H) {
        int r = i / H;
        size_t stride = (size_t)nseg * H;
        float s = xpart[i] + xpart[stride + i] + xpart[2 * stride + i] + xpart[3 * stride + i];
        int c = off[r + 1] - off[r];
        acc[i] = s / (float)(c > 0 ? c : 1);
    }
}

// ---------------- fused LSTM cell + l2norm of h and c ----------------
__global__ __launch_bounds__(256) void lstm_k(const float* __restrict__ x1, const float* __restrict__ x2,
                                              const float* __restrict__ hprev, const float* __restrict__ cprev,
                                              const float* __restrict__ Wih, const float* __restrict__ Whh,
                                              const float* __restrict__ bih, const float* __restrict__ bhh,
                                              float* __restrict__ hout, float* __restrict__ cout, int rows) {
    int r = blockIdx.x;
    if (r >= rows) return;
    __shared__ float xb[2 * H], hb[H], gb[4 * H], hv[H], cv[H];
    __shared__ float red[8];
    int t = threadIdx.x;
    for (int i = t; i < 2 * H; i += 256)
        xb[i] = (i < H) ? x1[(size_t)r * H + i] : x2[(size_t)r * H + i - H];
    if (t < H) hb[t] = hprev[(size_t)r * H + t];
    __syncthreads();
    for (int j = t; j < 4 * H; j += 256) {
        float s = bih[j] + bhh[j];
        const float* wi = Wih + (size_t)j * 2 * H;
        for (int k = 0; k < 2 * H; ++k) s += xb[k] * wi[k];
        const float* wh = Whh + (size_t)j * H;
        for (int k = 0; k < H; ++k) s += hb[k] * wh[k];
        gb[j] = s;
    }
    __syncthreads();
    if (t < H) {
        float ig = fsig(gb[t]);
        float fg = fsig(gb[H + t]);
        float gg = ftanh(gb[2 * H + t]);
        float og = fsig(gb[3 * H + t]);
        float c2 = fg * cprev[(size_t)r * H + t] + ig * gg;
        cv[t] = c2;
        hv[t] = og * ftanh(c2);
    }
    __syncthreads();
    float sh = 0.f, sc = 0.f;
    if (t < H) { sh = hv[t] * hv[t]; sc = cv[t] * cv[t]; }
    for (int o = 32; o > 0; o >>= 1) { sh += __shfl_down(sh, o); sc += __shfl_down(sc, o); }
    if ((t & 63) == 0) { red[t >> 6] = sh; red[4 + (t >> 6)] = sc; }
    __syncthreads();
    if (t == 0) {
        red[0] = 1.f / fmaxf(sqrtf(red[0] + red[1] + red[2] + red[3]), 1e-12f);
        red[4] = 1.f / fmaxf(sqrtf(red[4] + red[5] + red[6] + red[7]), 1e-12f);
    }
    __syncthreads();
    if (t < H) {
        hout[(size_t)r * H + t] = hv[t] * red[0];
        cout[(size_t)r * H + t] = cv[t] * red[4];
    }
}

// ---------------- fused small GRU + l2norm (+bf16 mirror) ----------------
__global__ __launch_bounds__(256) void gru_small_k(const float* __restrict__ x, const float* __restrict__ h,
                                                   const float* __restrict__ Wih, const float* __restrict__ Whh,
                                                   const float* __restrict__ bih, const float* __restrict__ bhh,
                                                   float* __restrict__ outp, u16* __restrict__ mirp, int rows) {
    int r = blockIdx.x;
    if (r >= rows) return;
    __shared__ float xb[H], hb[H], gi[3 * H], gh[3 * H], ov[H];
    __shared__ float red[4];
    int t = threadIdx.x;
    if (t < H) { xb[t] = x[(size_t)r * H + t]; hb[t] = h[(size_t)r * H + t]; }
    __syncthreads();
    for (int j = t; j < 3 * H; j += 256) {
        float si = bih[j], sh2 = bhh[j];
        const float* wi = Wih + (size_t)j * H;
        const float* wh = Whh + (size_t)j * H;
        for (int k = 0; k < H; ++k) { si += xb[k] * wi[k]; sh2 += hb[k] * wh[k]; }
        gi[j] = si; gh[j] = sh2;
    }
    __syncthreads();
    if (t < H) {
        float rr = fsig(gi[t] + gh[t]);
        float zz = fsig(gi[H + t] + gh[H + t]);
        float nn = ftanh(gi[2 * H + t] + rr * gh[2 * H + t]);
        ov[t] = (1.f - zz) * nn + zz * hb[t];
    }
    __syncthreads();
    float s = (t < H) ? ov[t] * ov[t] : 0.f;
    for (int o = 32; o > 0; o >>= 1) s += __shfl_down(s, o);
    if ((t & 63) == 0) red[t >> 6] = s;
    __syncthreads();
    if (t == 0) red[0] = 1.f / fmaxf(sqrtf(red[0] + red[1] + red[2] + red[3]), 1e-12f);
    __syncthreads();
    if (t < H) {
        float v = ov[t] * red[0];
        outp[(size_t)r * H + t] = v;
        mirp[(size_t)r * H + t] = f2bf(v);
    }
}

// ---------------- fused super-graph layer: gather + rrelu(agg@Wn + cur@Wsel) ----------------
__global__ __launch_bounds__(256) void sup_fused_k(const float* __restrict__ cur, const float* __restrict__ prel,
                                                   const int* __restrict__ soff, const int* __restrict__ sssrc,
                                                   const int* __restrict__ sset,
                                                   const float* __restrict__ Wn, const float* __restrict__ We,
                                                   const float* __restrict__ Wl, const int* __restrict__ indeg,
                                                   float* __restrict__ outp) {
    int r = blockIdx.x;
    __shared__ float ar[H], cr[H];
    int t = threadIdx.x;
    if (t < H) {
        int beg = soff[r], end = soff[r + 1];
        float acc = 0.f;
        for (int i = beg; i < end; ++i)
            acc += cur[(size_t)sssrc[i] * H + t] + prel[(size_t)sset[i] * H + t];
        ar[t] = acc;
        cr[t] = cur[(size_t)r * H + t];
    }
    __syncthreads();
    const float* W2 = (indeg[r] > 0) ? We : Wl;
    if (t < H) {
        float s = 0.f;
        for (int k = 0; k < H; ++k) s += ar[k] * Wn[(size_t)k * H + t] + cr[k] * W2[(size_t)k * H + t];
        outp[(size_t)r * H + t] = (s >= 0.f) ? s : s * SLOPE;
    }
}

// ---------------- entity message aggregation via CSR (wave per dst), 2-edge unrolled ----------------
__global__ __launch_bounds__(256) void ent_agg_b_k(const u16* __restrict__ cur, const u16* __restrict__ rel,
                                                   const int* __restrict__ eoff, const int* __restrict__ esrc,
                                                   const int* __restrict__ eet, u16* __restrict__ agg, int n) {
    int wave = threadIdx.x >> 6, lane = threadIdx.x & 63;
    int v = blockIdx.x * 4 + wave;
    if (v >= n) return;
    float a0 = 0.f, a1 = 0.f, a2 = 0.f, a3 = 0.f;
    bool act = lane < 50;
    int beg = eoff[v], end = eoff[v + 1];
    int i = beg;
    for (; i + 2 <= end; i += 2) {
        int e0 = esrc[i], t0 = eet[i];
        int e1 = esrc[i + 1], t1 = eet[i + 1];
        if (act) {
            uint2 h0 = ((const uint2*)(cur + (size_t)e0 * H))[lane];
            uint2 h1 = ((const uint2*)(cur + (size_t)e1 * H))[lane];
            uint2 r0 = ((const uint2*)(rel + (size_t)t0 * H))[lane];
            uint2 r1 = ((const uint2*)(rel + (size_t)t1 * H))[lane];
            a0 += bf2f(h0.x & 0xffff) + bf2f(r0.x & 0xffff) + bf2f(h1.x & 0xffff) + bf2f(r1.x & 0xffff);
            a1 += bf2f(h0.x >> 16) + bf2f(r0.x >> 16) + bf2f(h1.x >> 16) + bf2f(r1.x >> 16);
            a2 += bf2f(h0.y & 0xffff) + bf2f(r0.y & 0xffff) + bf2f(h1.y & 0xffff) + bf2f(r1.y & 0xffff);
            a3 += bf2f(h0.y >> 16) + bf2f(r0.y >> 16) + bf2f(h1.y >> 16) + bf2f(r1.y >> 16);
        }
    }
    if (i < end) {
        int e0 = esrc[i], t0 = eet[i];
        if (act) {
            uint2 h0 = ((const uint2*)(cur + (size_t)e0 * H))[lane];
            uint2 r0 = ((const uint2*)(rel + (size_t)t0 * H))[lane];
            a0 += bf2f(h0.x & 0xffff) + bf2f(r0.x & 0xffff);
            a1 += bf2f(h0.x >> 16) + bf2f(r0.x >> 16);
            a2 += bf2f(h0.y & 0xffff) + bf2f(r0.y & 0xffff);
            a3 += bf2f(h0.y >> 16) + bf2f(r0.y >> 16);
        }
    }
    if (act) {
        uint2 o; o.x = pk2(a0, a1); o.y = pk2(a2, a3);
        ((uint2*)(agg + (size_t)v * H))[lane] = o;
    }
}

// ---------------- B-persistent bf16 MFMA GEMM, split-k B staging + partial last col group ----------------
#define BSTR 108   // padded LDS row stride
__global__ __launch_bounds__(128) void gemm_bp_k(const u16* __restrict__ A1, const u16* __restrict__ A2,
                                                 const u16* __restrict__ B1, const u16* __restrict__ B2,
                                                 u16* __restrict__ Cm, int M, int Nc) {
    __shared__ __bf16 Bs[64 * BSTR];  // 13824 B
    const int tid = threadIdx.x;
    int idx2 = xcd_swz(blockIdx.x, gridDim.x);
    const int m0 = (idx2 >> 2) * 128;
    const int n0 = (idx2 & 3) * 64;
    const int nfb = (n0 + 16 >= Nc) ? 1 : 4;        // last col group: only 1 useful 16-col frag
    const int brows = (nfb == 1) ? 16 : 64;
    const int w = tid >> 6, lane = tid & 63;
    const int lr = lane & 15, lo = lane >> 4;
    const int mbase = m0 + w * 64;

    bf8 zb;
#pragma unroll
    for (int e = 0; e < 8; ++e) zb[e] = (__bf16)0.f;

    f32x4 acc[4][4];
#pragma unroll
    for (int i = 0; i < 4; ++i)
#pragma unroll
        for (int j = 0; j < 4; ++j)
#pragma unroll
            for (int e = 0; e < 4; ++e) acc[i][j][e] = 0.f;

    auto stageB = [&](const u16* Bp, int kbase, int nch) {
        for (int ch = tid; ch < brows * nch; ch += 128) {
            int n = ch / nch, q = ch - n * nch;
            int ng = n0 + n;
            uint4 v = make_uint4(0, 0, 0, 0);
            if (ng < Nc) v = *(const uint4*)(Bp + (size_t)ng * 200 + kbase + q * 8);
            *(uint4*)(&Bs[n * BSTR + q * 8]) = v;
        }
    };
    auto loadA = [&](bf8* buf, const u16* Ap, int kt7) {
        int kk = kt7 * 32 + lo * 8;
        bool kv = kk < 200;
#pragma unroll
        for (int mf = 0; mf < 4; ++mf) {
            int m = mbase + mf * 16 + lr;
            bf8 v = zb;
            if (kv && m < M) v = *(const bf8*)(Ap + (size_t)m * 200 + kk);
            buf[mf] = v;
        }
    };
    auto mmaStep = [&](bf8* a, int kt7, int kbase) {
        int kk = kt7 * 32 + lo * 8;
        int kcl = (kk < 200) ? (kk - kbase) : 0;
#pragma unroll
        for (int nf = 0; nf < 4; ++nf) {
            if (nf < nfb) {
                bf8 b = *(const bf8*)(&Bs[(nf * 16 + lr) * BSTR + kcl]);
#pragma unroll
                for (int mf = 0; mf < 4; ++mf)
                    acc[mf][nf] = __builtin_amdgcn_mfma_f32_16x16x32_bf16(a[mf], b, acc[mf][nf], 0, 0, 0);
            }
        }
    };

    bf8 a0[4], a1[4];
    stageB(B1, 0, 12);
    __syncthreads();
    loadA(a0, A1, 0);
    loadA(a1, A1, 1); mmaStep(a0, 0, 0);
    loadA(a0, A1, 2); mmaStep(a1, 1, 0);
    loadA(a1, A1, 3); mmaStep(a0, 2, 0);
    __syncthreads();
    stageB(B1, 96, 13);
    __syncthreads();
    loadA(a0, A1, 4); mmaStep(a1, 3, 96);
    loadA(a1, A1, 5); mmaStep(a0, 4, 96);
    loadA(a0, A1, 6); mmaStep(a1, 5, 96);
    loadA(a1, A2, 0); mmaStep(a0, 6, 96);
    __syncthreads();
    stageB(B2, 0, 12);
    __syncthreads();
    loadA(a0, A2, 1); mmaStep(a1, 0, 0);
    loadA(a1, A2, 2); mmaStep(a0, 1, 0);
    loadA(a0, A2, 3); mmaStep(a1, 2, 0);
    __syncthreads();
    stageB(B2, 96, 13);
    __syncthreads();
    loadA(a1, A2, 4); mmaStep(a0, 3, 96);
    loadA(a0, A2, 5); mmaStep(a1, 4, 96);
    loadA(a1, A2, 6); mmaStep(a0, 5, 96);
    mmaStep(a1, 6, 96);

#pragma unroll
    for (int mf = 0; mf < 4; ++mf) {
#pragma unroll
        for (int r = 0; r < 4; ++r) {
            int m = mbase + mf * 16 + lo * 4 + r;
            if (m >= M) continue;
#pragma unroll
            for (int nf = 0; nf < 4; ++nf) {
                if (nf >= nfb) continue;
                int n = n0 + nf * 16 + lr;
                if (n >= Nc) continue;
                float v = acc[mf][nf][r];
                v = (v >= 0.f) ? v : v * SLOPE;
                Cm[(size_t)m * Nc + n] = f2bf(v);
            }
        }
    }
}

// ---------------- fixup for zero-indeg rows: out[row] = rrelu(h[row] @ Wl), bf16 io ----------------
__global__ __launch_bounds__(256) void fixup_b_k(const u16* __restrict__ h, const float* __restrict__ Wl,
                                                 const int* __restrict__ zl, const int* __restrict__ nz,
                                                 u16* __restrict__ outp) {
    __shared__ float xr[H];
    int nzv = *nz;
    for (int z = blockIdx.x; z < nzv; z += gridDim.x) {
        int row = zl[z];
        if (threadIdx.x < H) xr[threadIdx.x] = bf2f(h[(size_t)row * H + threadIdx.x]);
        __syncthreads();
        if (threadIdx.x < H) {
            float s = 0.f;
            for (int k = 0; k < H; ++k) s += xr[k] * Wl[(size_t)k * H + threadIdx.x];
            outp[(size_t)row * H + threadIdx.x] = f2bf((s >= 0.f) ? s : s * SLOPE);
        }
        __syncthreads();
    }
}

// ---------------- W-in-LDS entity GRU: padded LDS (204), bf16 h for z*h, bf16 out ----------------
#define GCG2 13       // col groups of 16
#define GTPB 6        // row tiles (128 rows each) per block
#define WSTR 204      // padded Ws row stride
__global__ __launch_bounds__(256, 4) void gru_wlds_k(const u16* __restrict__ Xb, const u16* __restrict__ Hb,
                                                     const u16* __restrict__ Wb,
                                                     const float* __restrict__ bih, const float* __restrict__ bhh,
                                                     u16* __restrict__ Outb, int M) {
    __shared__ __bf16 Ws[6][16 * WSTR];   // 39168 B
    const int tid = threadIdx.x;
    int idx2 = xcd_swz(blockIdx.x, gridDim.x);
    const int cg = idx2 % GCG2;
    const int rb = idx2 / GCG2;
    const int w = tid >> 6, lane = tid & 63;
    const int lr = lane & 15, lo = lane >> 4;
    const int c0 = cg * 16;

    for (int ch = tid; ch < 2400; ch += 256) {
        int s = ch / 400;
        int rem = ch - s * 400;
        int col = rem / 25, q = rem - (rem / 25) * 25;
        int cc = c0 + col; if (cc > 199) cc = 199;
        uint4 v = *(const uint4*)(Wb + (size_t)(s * 200 + cc) * 200 + q * 8);
        *(uint4*)(&Ws[s][col * WSTR + q * 8]) = v;
    }
    __syncthreads();

    int c = c0 + lr;
    const bool cvalid = c < 200;
    const int cc = cvalid ? c : 199;
    const float b0 = bih[cc], b1 = bih[200 + cc], b2 = bih[400 + cc];
    const float b3 = bhh[cc], b4 = bhh[200 + cc], b5 = bhh[400 + cc];

    bf8 zb;
#pragma unroll
    for (int e = 0; e < 8; ++e) zb[e] = (__bf16)0.f;

    for (int tile = 0; tile < GTPB; ++tile) {
        int mbase = (rb * GTPB + tile) * 128 + w * 32;
        if (mbase >= M) break;
        int m0r = mbase + lr;      if (m0r >= M) m0r = M - 1;
        int m1r = mbase + 16 + lr; if (m1r >= M) m1r = M - 1;
        const u16* Xp0 = Xb + (size_t)m0r * 200 + lo * 8;
        const u16* Xp1 = Xb + (size_t)m1r * 200 + lo * 8;
        const u16* Hp0 = Hb + (size_t)m0r * 200 + lo * 8;
        const u16* Hp1 = Hb + (size_t)m1r * 200 + lo * 8;

        f32x4 acc[6][2];
#pragma unroll
        for (int s = 0; s < 6; ++s)
#pragma unroll
            for (int i = 0; i < 2; ++i)
#pragma unroll
                for (int e = 0; e < 4; ++e) acc[s][i][e] = 0.f;

#pragma unroll
        for (int kt = 0; kt < 7; ++kt) {
            const int koff = kt * 32;
            const bool kv = (kt < 6) || (lo == 0);
            const int kcl = kv ? (koff + lo * 8) : 0;
            bf8 xa0 = zb, xa1 = zb, ha0 = zb, ha1 = zb;
            if (kv) {
                xa0 = *(const bf8*)(Xp0 + koff);
                xa1 = *(const bf8*)(Xp1 + koff);
                ha0 = *(const bf8*)(Hp0 + koff);
                ha1 = *(const bf8*)(Hp1 + koff);
            }
#pragma unroll
            for (int s = 0; s < 6; ++s) {
                bf8 wv = *(const bf8*)(&Ws[s][lr * WSTR + kcl]);
                bf8 a0f = (s < 3) ? xa0 : ha0;
                bf8 a1f = (s < 3) ? xa1 : ha1;
                acc[s][0] = __builtin_amdgcn_mfma_f32_16x16x32_bf16(a0f, wv, acc[s][0], 0, 0, 0);
                acc[s][1] = __builtin_amdgcn_mfma_f32_16x16x32_bf16(a1f, wv, acc[s][1], 0, 0, 0);
            }
        }
        if (cvalid) {
#pragma unroll
            for (int mf = 0; mf < 2; ++mf) {
#pragma unroll
                for (int r = 0; r < 4; ++r) {
                    int m = mbase + mf * 16 + lo * 4 + r;
                    if (m >= M) continue;
                    float ir = acc[0][mf][r] + b0;
                    float iz = acc[1][mf][r] + b1;
                    float in_ = acc[2][mf][r] + b2;
                    float hr = acc[3][mf][r] + b3;
                    float hz = acc[4][mf][r] + b4;
                    float hn = acc[5][mf][r] + b5;
                    float rr = fsig(ir + hr);
                    float zz = fsig(iz + hz);
                    float nn = ftanh(in_ + rr * hn);
                    float hvv = bf2f(Hb[(size_t)m * 200 + c]);
                    Outb[(size_t)m * 200 + c] = f2bf((1.f - zz) * nn + zz * hvv);
                }
            }
        }
    }
}

// =========================== host orchestration ===========================
extern "C" void kernel_launch(void* const* d_in, const int* in_sizes, int n_in,
                              void* d_out, int out_size, void* d_ws, size_t ws_size,
                              hipStream_t stream) {
    (void)in_sizes; (void)n_in; (void)out_size; (void)ws_size;
    const int* src  = (const int*)d_in[0];
    const int* dst  = (const int*)d_in[1];
    const int* etyp = (const int*)d_in[2];
    const int* rte  = (const int*)d_in[3];
    const int* rseg = (const int*)d_in[4];
    const int* ssrc = (const int*)d_in[5];
    const int* sdst = (const int*)d_in[6];
    const int* setp = (const int*)d_in[7];
    const int* srte = (const int*)d_in[8];
    const int* srseg= (const int*)d_in[9];
    const float* dyn     = (const float*)d_in[10];
    const float* emb_rel = (const float*)d_in[11];
    const float* p_rel   = (const float*)d_in[12];
    const float* Wih1 = (const float*)d_in[13]; const float* Whh1 = (const float*)d_in[14];
    const float* bih1 = (const float*)d_in[15]; const float* bhh1 = (const float*)d_in[16];
    const float* Wih2 = (const float*)d_in[17]; const float* Whh2 = (const float*)d_in[18];
    const float* bih2 = (const float*)d_in[19]; const float* bhh2 = (const float*)d_in[20];
    const float* Wih3 = (const float*)d_in[21]; const float* Whh3 = (const float*)d_in[22];
    const float* bih3 = (const float*)d_in[23]; const float* bhh3 = (const float*)d_in[24];
    const float* Wihe = (const float*)d_in[25]; const float* Whhe = (const float*)d_in[26];
    const float* bihe = (const float*)d_in[27]; const float* bhhe = (const float*)d_in[28];
    const float* Wn  = (const float*)d_in[29];
    const float* Wl  = (const float*)d_in[30];
    const float* We  = (const float*)d_in[31];
    const float* sWn = (const float*)d_in[32];
    const float* sWl = (const float*)d_in[33];
    const float* sWe = (const float*)d_in[34];

    float* out = (float*)d_out;
    const size_t NH = (size_t)N_NODES * H;
    float* relout = out + 3 * NH;

    char* wp = (char*)d_ws;
    auto carve = [&](size_t bytes) -> void* {
        void* p = (void*)wp;
        wp += (bytes + 255) & ~(size_t)255;
        return p;
    };
    u16* aggB = (u16*)carve(NH * 2);
    u16* m0b  = (u16*)carve(NH * 2);
    u16* m1b  = (u16*)carve(NH * 2);
    u16* hmir = (u16*)carve(NH * 2);
    u16* gob  = (u16*)carve(NH * 2);   // bf16 GRU output
    u16* relm = (u16*)carve((size_t)R2 * H * 2);
    u16* wtB  = (u16*)carve((size_t)400000 * 2);
    float* h0a  = (float*)carve((size_t)R2 * H * 4);
    float* c0b  = (float*)carve((size_t)R2 * H * 4);
    float* xin  = (float*)carve((size_t)R2 * H * 4);
    float* xpart= (float*)carve((size_t)4 * R2 * H * 4);
    float* srelA= (float*)carve((size_t)R2 * H * 4);
    float* srelB= (float*)carve((size_t)R2 * H * 4);
    float* sxin = (float*)carve((size_t)SR * H * 4);
    float* p_h  = (float*)carve((size_t)SR * H * 4);
    float* p_c  = (float*)carve((size_t)SR * H * 4);
    // persistent (used inside t-loop) batched CSR data
    int* eoff3  = (int*)carve((size_t)3 * (N_NODES + 1) * 4);
    int* esrcp3 = (int*)carve((size_t)3 * E_EDGES * 4);
    int* eetp3  = (int*)carve((size_t)3 * E_EDGES * 4);
    int* zl3    = (int*)carve((size_t)3 * N_NODES * 4);
    int* nz3    = (int*)carve(3 * 4);
    int* rcsr3  = (int*)carve((size_t)3 * (R2 + 1) * 4);
    int* rper3  = (int*)carve((size_t)3 * R2E * 4);
    int* sindeg3= (int*)carve((size_t)3 * R2 * 4);
    int* hist3  = (int*)carve((size_t)3 * NB * R2 * 4);
    int* offb3  = (int*)carve((size_t)3 * NB * R2 * 4);
    int* soff3  = (int*)carve((size_t)3 * (R2 + 1) * 4);
    int* scur3  = (int*)carve((size_t)3 * R2 * 4);
    int* sssrc3 = (int*)carve((size_t)3 * SE_EDGES * 4);
    int* sset3  = (int*)carve((size_t)3 * SE_EDGES * 4);
    int* bsum3  = (int*)carve((size_t)3 * NCH * 4);
    int* boff3  = (int*)carve((size_t)3 * NCH * 4);
    // transient (pre-loop only) arrays aliased into loop-phase buffers
    int* ecnt3 = (int*)m0b;
    int* rcnt3 = (int*)m0b + 3 * N_NODES;
    int* ecur3 = (int*)aggB;
    int* rcur3 = (int*)aggB + 3 * N_NODES;

    // ---- weights -> bf16 ----
    dim3 wg4(157, 4);
    wconv4_k<<<wg4, 256, 0, stream>>>(Wn, We, Wn + 40000, We + 40000, wtB);
    wconv2_k<<<938, 256, 0, stream>>>(Wihe, Whhe, wtB + 160000);

    // ---- batched graph preprocessing ----
    hipMemsetAsync(ecnt3, 0, (size_t)3 * N_NODES * 4, stream);
    hipMemsetAsync(rcnt3, 0, (size_t)3 * R2 * 4, stream);
    hipMemsetAsync(nz3, 0, 3 * 4, stream);
    hipMemsetAsync(sindeg3, 0, (size_t)3 * R2 * 4, stream);
    cnt3_k<<<(3 * E_EDGES + 255) / 256, 256, 0, stream>>>(dst, 3 * E_EDGES, E_EDGES, N_NODES, ecnt3);
    scanA_k<<<3 * NCH, 256, 0, stream>>>(ecnt3, bsum3, N_NODES);
    scanB_k<<<3, 128, 0, stream>>>(bsum3, boff3, eoff3, N_NODES);
    scanC_k<<<3 * NCH, 256, 0, stream>>>(ecnt3, boff3, eoff3, ecur3, N_NODES);
    scatter3_k<<<(3 * E_EDGES + 255) / 256, 256, 0, stream>>>(dst, src, etyp, ecur3, esrcp3, eetp3,
                                                             E_EDGES, N_NODES, 3 * E_EDGES);
    {
        int bpt = (N_NODES + 255) / 256;
        zlist3b_k<<<3 * bpt, 256, 0, stream>>>(ecnt3, zl3, nz3, N_NODES, bpt);
    }
    hist3_k<<<3 * NB, 256, 0, stream>>>(rseg, hist3, rcnt3);
    scan3_k<<<3, 1024, 0, stream>>>(rcnt3, rcsr3, rcur3, R2);
    offs3_k<<<3 * R2, 64, 0, stream>>>(hist3, rcsr3, offb3);
    part3_k<<<3 * NB, 256, 0, stream>>>(rseg, rte, offb3, rper3);
    cnt3_k<<<(3 * SE_EDGES + 255) / 256, 256, 0, stream>>>(sdst, 3 * SE_EDGES, SE_EDGES, R2, sindeg3);
    scan3_k<<<3, 1024, 0, stream>>>(sindeg3, soff3, scur3, R2);
    scatter3_k<<<(3 * SE_EDGES + 255) / 256, 256, 0, stream>>>(sdst, ssrc, setp, scur3, sssrc3, sset3,
                                                              SE_EDGES, R2, 3 * SE_EDGES);

    // h = l2norm(dynamic_emb) -> out+NH (scratch fp32) + hmir
    l2norm_k<<<(N_NODES + 3) / 4, 256, 0, stream>>>(dyn, out + NH, hmir, N_NODES);

    const int gw  = 4 * ((N_NODES + 127) / 128);                       // 3128 blocks of 128 thr
    const int NRB2 = (N_NODES + GTPB * 128 - 1) / (GTPB * 128);        // 131
    const int gwg = GCG2 * NRB2;                                       // 1703 blocks of 256 thr

    for (int t = 0; t < T_STEPS; ++t) {
        const int* srte_t = srte + (size_t)t * S2E;
        const int* srseg_t= srseg + (size_t)t * S2E;
        const int* eoff_t = eoff3 + (size_t)t * (N_NODES + 1);
        const int* esrc_t = esrcp3 + (size_t)t * E_EDGES;
        const int* eet_t  = eetp3 + (size_t)t * E_EDGES;
        const int* zl_t   = zl3 + (size_t)t * N_NODES;
        const int* nz_t   = nz3 + t;
        const int* rcsr_t = rcsr3 + (size_t)t * (R2 + 1);
        const int* rper_t = rper3 + (size_t)t * R2E;
        const int* sind_t = sindeg3 + (size_t)t * R2;
        const int* soff_t = soff3 + (size_t)t * (R2 + 1);
        const int* sssrc_t= sssrc3 + (size_t)t * SE_EDGES;
        const int* sset_t = sset3 + (size_t)t * SE_EDGES;

        float* hist = out + (size_t)t * NH;
        float* rel_t = relout + (size_t)t * R2 * H;
        const float* hprev = (t == 0) ? emb_rel : relout + (size_t)(t - 1) * R2 * H;
        const float* cprev = (t == 0) ? xin : c0b;
        const float* php   = (t == 0) ? p_rel : p_h;
        const float* pcp   = (t == 0) ? sxin : p_c;

        // ---- x_input = seg_mean(h[r_to_e], r_seg, R2): 4-way disjoint partials + finalize ----
        seg_mean_part_k<<<R2 * 4, 256, 0, stream>>>(hmir, rper_t, rcsr_t, xpart, R2);
        seg_fin_k<<<(R2 * H + 255) / 256, 256, 0, stream>>>(xpart, rcsr_t, xin, R2);
        // ---- LSTM1 ----
        lstm_k<<<R2, 256, 0, stream>>>(emb_rel, xin, hprev, cprev, Wih1, Whh1, bih1, bhh1, h0a, c0b, R2);
        // ---- sx = seg_mean(h_0[s_r_to_e], s_r_seg, SR): fused single kernel ----
        seg_mean_sr_k<<<SR, 256, 0, stream>>>(h0a, srte_t, srseg_t, sxin);
        // ---- LSTM2 ----
        lstm_k<<<SR, 256, 0, stream>>>(p_rel, sxin, php, pcp, Wih2, Whh2, bih2, bhh2, p_h, p_c, SR);
        // ---- super RGCN (2 fused layers) ----
        sup_fused_k<<<R2, 256, 0, stream>>>(h0a, p_h, soff_t, sssrc_t, sset_t, sWn, sWe, sWl, sind_t, srelA);
        sup_fused_k<<<R2, 256, 0, stream>>>(srelA, p_h, soff_t, sssrc_t, sset_t,
                                            sWn + H * H, sWe + H * H, sWl + H * H, sind_t, srelB);
        l2norm_k<<<(R2 + 3) / 4, 256, 0, stream>>>(srelB, srelB, (u16*)nullptr, R2);
        // ---- rel GRU -> rel_embs[t] (+bf16 mirror) ----
        gru_small_k<<<R2, 256, 0, stream>>>(srelB, h0a, Wih3, Whh3, bih3, bhh3, rel_t, relm, R2);

        // ---- entity layer 0 (bf16 in, bf16 out) ----
        ent_agg_b_k<<<(N_NODES + 3) / 4, 256, 0, stream>>>(hmir, relm, eoff_t, esrc_t, eet_t, aggB, N_NODES);
        gemm_bp_k<<<gw, 128, 0, stream>>>(aggB, hmir, wtB, wtB + 40000, m0b, N_NODES, H);
        fixup_b_k<<<2048, 256, 0, stream>>>(hmir, Wl, zl_t, nz_t, m0b);
        // ---- entity layer 1 ----
        ent_agg_b_k<<<(N_NODES + 3) / 4, 256, 0, stream>>>(m0b, relm, eoff_t, esrc_t, eet_t, aggB, N_NODES);
        gemm_bp_k<<<gw, 128, 0, stream>>>(aggB, m0b, wtB + 80000, wtB + 120000, m1b, N_NODES, H);
        fixup_b_k<<<2048, 256, 0, stream>>>(m0b, Wl + H * H, zl_t, nz_t, m1b);
        l2norm_b_k<<<(N_NODES + 3) / 4, 256, 0, stream>>>(m1b, N_NODES);

        // ---- W-in-LDS entity GRU (bf16 out) -> l2norm to fp32 hist + hmir ----
        gru_wlds_k<<<gwg, 256, 0, stream>>>(m1b, hmir, wtB + 160000, bihe, bhhe, gob, N_NODES);
        l2norm_bb_k<<<(N_NODES + 3) / 4, 256, 0, stream>>>(gob, hist, hmir, N_NODES);
    }
}

// Round 17
// 2562.044 us; speedup vs baseline: 1.4020x; 1.4020x over previous
//
#include <hip/hip_runtime.h>
#include <math.h>

#define N_NODES 100000
#define H 200
#define R2 500
#define T_STEPS 3
#define E_EDGES 300000
#define R2E 400000
#define SE_EDGES 4000
#define SR 8
#define S2E 8000
#define SLOPE 0.22916666666666666f
#define NB 64            // partition blocks per timestep for r_seg
#define RCHUNK ((R2E + NB - 1) / NB)
#define NCH 128          // chunks per timestep for entity CSR scan
#define CHSZ ((N_NODES + NCH - 1) / NCH)   // 782
#define SPT  ((CHSZ + 255) / 256)          // 4 elems per thread in scan phases

typedef unsigned short u16;
typedef unsigned int u32;
typedef __bf16 bf8 __attribute__((ext_vector_type(8)));
typedef float f32x4 __attribute__((ext_vector_type(4)));

static __device__ __forceinline__ float fsig(float x) { return 1.f / (1.f + __expf(-x)); }
static __device__ __forceinline__ float ftanh(float x) {
    float e = __expf(-2.f * fabsf(x));
    float t = (1.f - e) / (1.f + e);
    return (x >= 0.f) ? t : -t;
}
static __device__ __forceinline__ float bf2f(u32 lo16) {
    u32 v = lo16 << 16; float f; __builtin_memcpy(&f, &v, 4); return f;
}
static __device__ __forceinline__ u16 f2bf(float a) {
    __bf16 x = (__bf16)a; u16 u; __builtin_memcpy(&u, &x, 2); return u;
}
static __device__ __forceinline__ u32 pk2(float a, float b) {
    return (u32)f2bf(a) | ((u32)f2bf(b) << 16);
}
// bijective XCD swizzle (m204)
static __device__ __forceinline__ int xcd_swz(int b, int nwg) {
    int q = nwg >> 3, r = nwg & 7;
    int xcd = b & 7, u = b >> 3;
    int start = xcd * q + (xcd < r ? xcd : r);
    return start + u;
}

// ---------------- l2 normalize rows fp32 (+optional bf16 mirror); src may alias dst ----------------
__global__ __launch_bounds__(256) void l2norm_k(const float* __restrict__ src, float* __restrict__ dst,
                                                u16* __restrict__ mir, int rows) {
    int wave = threadIdx.x >> 6, lane = threadIdx.x & 63;
    int r = blockIdx.x * 4 + wave;
    if (r >= rows) return;
    float4 v = make_float4(0.f, 0.f, 0.f, 0.f);
    if (lane < 50) v = *(const float4*)(src + (size_t)r * H + lane * 4);
    float s = v.x * v.x + v.y * v.y + v.z * v.z + v.w * v.w;
    for (int o = 32; o > 0; o >>= 1) s += __shfl_down(s, o);
    float rn = 1.f / fmaxf(sqrtf(__shfl(s, 0)), 1e-12f);
    if (lane < 50) {
        float4 o4 = make_float4(v.x * rn, v.y * rn, v.z * rn, v.w * rn);
        *(float4*)(dst + (size_t)r * H + lane * 4) = o4;
        if (mir) {
            uint2 u; u.x = pk2(o4.x, o4.y); u.y = pk2(o4.z, o4.w);
            *(uint2*)(mir + (size_t)r * H + lane * 4) = u;
        }
    }
}

// ---------------- l2 normalize bf16 rows in place ----------------
__global__ __launch_bounds__(256) void l2norm_b_k(u16* __restrict__ buf, int rows) {
    int wave = threadIdx.x >> 6, lane = threadIdx.x & 63;
    int r = blockIdx.x * 4 + wave;
    if (r >= rows) return;
    uint2 u = make_uint2(0, 0);
    if (lane < 50) u = *(const uint2*)(buf + (size_t)r * H + lane * 4);
    float x0 = bf2f(u.x & 0xffff), x1 = bf2f(u.x >> 16);
    float x2 = bf2f(u.y & 0xffff), x3 = bf2f(u.y >> 16);
    float s = x0 * x0 + x1 * x1 + x2 * x2 + x3 * x3;
    for (int o = 32; o > 0; o >>= 1) s += __shfl_down(s, o);
    float rn = 1.f / fmaxf(sqrtf(__shfl(s, 0)), 1e-12f);
    if (lane < 50) {
        uint2 o2; o2.x = pk2(x0 * rn, x1 * rn); o2.y = pk2(x2 * rn, x3 * rn);
        *(uint2*)(buf + (size_t)r * H + lane * 4) = o2;
    }
}

// ---------------- l2 normalize bf16 src -> fp32 dst + bf16 mirror ----------------
__global__ __launch_bounds__(256) void l2norm_bb_k(const u16* __restrict__ src, float* __restrict__ dst,
                                                   u16* __restrict__ mir, int rows) {
    int wave = threadIdx.x >> 6, lane = threadIdx.x & 63;
    int r = blockIdx.x * 4 + wave;
    if (r >= rows) return;
    uint2 u = make_uint2(0, 0);
    if (lane < 50) u = *(const uint2*)(src + (size_t)r * H + lane * 4);
    float x0 = bf2f(u.x & 0xffff), x1 = bf2f(u.x >> 16);
    float x2 = bf2f(u.y & 0xffff), x3 = bf2f(u.y >> 16);
    float s = x0 * x0 + x1 * x1 + x2 * x2 + x3 * x3;
    for (int o = 32; o > 0; o >>= 1) s += __shfl_down(s, o);
    float rn = 1.f / fmaxf(sqrtf(__shfl(s, 0)), 1e-12f);
    if (lane < 50) {
        float4 o4 = make_float4(x0 * rn, x1 * rn, x2 * rn, x3 * rn);
        *(float4*)(dst + (size_t)r * H + lane * 4) = o4;
        uint2 o2; o2.x = pk2(o4.x, o4.y); o2.y = pk2(o4.z, o4.w);
        *(uint2*)(mir + (size_t)r * H + lane * 4) = o2;
    }
}

// ---------------- weight converts ----------------
__global__ void wconv4_k(const float* __restrict__ W0, const float* __restrict__ W1,
                         const float* __restrict__ W2, const float* __restrict__ W3,
                         u16* __restrict__ o) {
    int m = blockIdx.y;
    const float* W = (m == 0) ? W0 : (m == 1) ? W1 : (m == 2) ? W2 : W3;
    int i = blockIdx.x * 256 + threadIdx.x;
    if (i < 40000) { int n = i / 200, k = i - n * 200; o[m * 40000 + i] = f2bf(W[k * 200 + n]); }
}
__global__ void wconv2_k(const float* __restrict__ Wa, const float* __restrict__ Wb, u16* __restrict__ o) {
    int i = blockIdx.x * 256 + threadIdx.x;
    if (i < 240000) o[i] = f2bf(i < 120000 ? Wa[i] : Wb[i - 120000]);
}

// ---------------- batched counting over 3 timesteps ----------------
__global__ void cnt3_k(const int* __restrict__ d, int total, int per_t, int stride, int* __restrict__ cnt) {
    int i = blockIdx.x * 256 + threadIdx.x;
    if (i < total) { int t = i / per_t; atomicAdd(&cnt[t * stride + d[i]], 1); }
}

// ---------------- batched segment counts with LDS hierarchy ----------------
__global__ __launch_bounds__(256) void seg_cnt3_k(const int* __restrict__ seg, int per_t, int nseg,
                                                  int blocks_per_t, int* __restrict__ cnt) {
    __shared__ int lc[500];
    int t = blockIdx.x / blocks_per_t;
    int pb = blockIdx.x - t * blocks_per_t;
    const int* s = seg + (size_t)t * per_t;
    int* c = cnt + (size_t)t * nseg;
    for (int i = threadIdx.x; i < nseg; i += 256) lc[i] = 0;
    __syncthreads();
    int chunk = (per_t + blocks_per_t - 1) / blocks_per_t;
    int beg = pb * chunk;
    int end = beg + chunk; if (end > per_t) end = per_t;
    for (int i = beg + threadIdx.x; i < end; i += 256) atomicAdd(&lc[s[i]], 1);
    __syncthreads();
    for (int i = threadIdx.x; i < nseg; i += 256) if (lc[i]) atomicAdd(&c[i], lc[i]);
}

// ---------------- r_seg partition: per-block histogram + totals ----------------
__global__ __launch_bounds__(256) void hist3_k(const int* __restrict__ seg,
                                               int* __restrict__ hist, int* __restrict__ cnt) {
    __shared__ int lc[R2];
    int t = blockIdx.x / NB;
    int pb = blockIdx.x - t * NB;
    const int* s = seg + (size_t)t * R2E;
    for (int i = threadIdx.x; i < R2; i += 256) lc[i] = 0;
    __syncthreads();
    int beg = pb * RCHUNK;
    int end = beg + RCHUNK; if (end > R2E) end = R2E;
    for (int i = beg + threadIdx.x; i < end; i += 256) atomicAdd(&lc[s[i]], 1);
    __syncthreads();
    int* hrow = hist + (size_t)(t * NB + pb) * R2;
    int* c = cnt + (size_t)t * R2;
    for (int i = threadIdx.x; i < R2; i += 256) {
        hrow[i] = lc[i];
        if (lc[i]) atomicAdd(&c[i], lc[i]);
    }
}

// ---------------- small batched CSR scan (single block per t; for nseg<=1000) ----------------
__global__ __launch_bounds__(1024) void scan3_k(const int* __restrict__ cntA, int* __restrict__ offA,
                                                int* __restrict__ curA, int n) {
    const int b = blockIdx.x;
    const int* cnt = cntA + (size_t)b * n;
    int* off = offA + (size_t)b * (n + 1);
    int* cur = curA + (size_t)b * n;
    __shared__ int part[1024];
    int tid = threadIdx.x;
    int per = (n + 1023) / 1024;
    int s0 = tid * per;
    int e0 = s0 + per; if (e0 > n) e0 = n;
    int sum = 0;
    for (int i = s0; i < e0; ++i) sum += cnt[i];
    part[tid] = sum;
    __syncthreads();
    for (int d = 1; d < 1024; d <<= 1) {
        int v = (tid >= d) ? part[tid - d] : 0;
        __syncthreads();
        part[tid] += v;
        __syncthreads();
    }
    int excl = (tid == 0) ? 0 : part[tid - 1];
    for (int i = s0; i < e0; ++i) { off[i] = excl; cur[i] = excl; excl += cnt[i]; }
    if (tid == 1023) off[n] = excl;
}

// ---------------- multi-block entity CSR scan: phase A (chunk sums) ----------------
__global__ __launch_bounds__(256) void scanA_k(const int* __restrict__ cntA, int* __restrict__ bsum, int n) {
    int b = blockIdx.x;
    int t = b / NCH, ch = b - t * NCH;
    const int* cnt = cntA + (size_t)t * n;
    int base = ch * CHSZ;
    int cend = base + CHSZ; if (cend > n) cend = n;
    int s0 = base + threadIdx.x * SPT;
    int e0 = s0 + SPT; if (e0 > cend) e0 = cend;
    int sum = 0;
    for (int i = s0; i < e0 && i < cend; ++i) sum += cnt[i];
    __shared__ int red[256];
    red[threadIdx.x] = (s0 < cend) ? sum : 0;
    __syncthreads();
    for (int o = 128; o > 0; o >>= 1) {
        if (threadIdx.x < o) red[threadIdx.x] += red[threadIdx.x + o];
        __syncthreads();
    }
    if (threadIdx.x == 0) bsum[t * NCH + ch] = red[0];
}

// ---------------- phase B: exclusive scan of chunk sums per timestep (+ write off[n]) ----------------
__global__ __launch_bounds__(128) void scanB_k(const int* __restrict__ bsum, int* __restrict__ boff,
                                               int* __restrict__ offA, int n) {
    int t = blockIdx.x;
    int tid = threadIdx.x;  // 0..127
    __shared__ int part[128];
    int v = bsum[t * NCH + tid];
    part[tid] = v;
    __syncthreads();
    for (int d = 1; d < 128; d <<= 1) {
        int u = (tid >= d) ? part[tid - d] : 0;
        __syncthreads();
        part[tid] += u;
        __syncthreads();
    }
    boff[t * NCH + tid] = part[tid] - v;   // exclusive
    if (tid == 127) offA[(size_t)t * (n + 1) + n] = part[127];
}

// ---------------- phase C: per-chunk scan + carry, write off/cur ----------------
__global__ __launch_bounds__(256) void scanC_k(const int* __restrict__ cntA, const int* __restrict__ boff,
                                               int* __restrict__ offA, int* __restrict__ curA, int n) {
    int b = blockIdx.x;
    int t = b / NCH, ch = b - t * NCH;
    const int* cnt = cntA + (size_t)t * n;
    int* off = offA + (size_t)t * (n + 1);
    int* cur = curA + (size_t)t * n;
    int base = ch * CHSZ;
    int cend = base + CHSZ; if (cend > n) cend = n;
    int s0 = base + threadIdx.x * SPT;
    int e0 = s0 + SPT; if (e0 > cend) e0 = cend;
    int sum = 0;
    for (int i = s0; i < e0 && i < cend; ++i) sum += cnt[i];
    __shared__ int part[256];
    int my = (s0 < cend) ? sum : 0;
    part[threadIdx.x] = my;
    __syncthreads();
    for (int d = 1; d < 256; d <<= 1) {
        int u = (threadIdx.x >= d) ? part[threadIdx.x - d] : 0;
        __syncthreads();
        part[threadIdx.x] += u;
        __syncthreads();
    }
    int excl = boff[t * NCH + ch] + part[threadIdx.x] - my;
    for (int i = s0; i < e0 && i < cend; ++i) {
        off[i] = excl; cur[i] = excl; excl += cnt[i];
    }
}

// ---------------- r_seg partition: per-(block,seg) offsets via wave scan ----------------
__global__ __launch_bounds__(64) void offs3_k(const int* __restrict__ hist, const int* __restrict__ csr,
                                              int* __restrict__ offb) {
    int b = blockIdx.x;            // 0..3*R2-1
    int t = b / R2, s = b - t * R2;
    int lane = threadIdx.x;        // 0..63 = block index
    int v = hist[(size_t)(t * NB + lane) * R2 + s];
    int pre = v;
    for (int o = 1; o < 64; o <<= 1) {
        int u = __shfl_up(pre, o);
        if (lane >= o) pre += u;
    }
    int base = csr[(size_t)t * (R2 + 1) + s];
    offb[(size_t)(t * NB + lane) * R2 + s] = base + pre - v;
}

// ---------------- r_seg partition: scatter with LDS counters ----------------
__global__ __launch_bounds__(256) void part3_k(const int* __restrict__ seg, const int* __restrict__ val,
                                               const int* __restrict__ offb, int* __restrict__ outp) {
    __shared__ int cur[R2];
    int t = blockIdx.x / NB;
    int pb = blockIdx.x - t * NB;
    const int* s = seg + (size_t)t * R2E;
    const int* v = val + (size_t)t * R2E;
    const int* ob = offb + (size_t)(t * NB + pb) * R2;
    int* o = outp + (size_t)t * R2E;
    for (int i = threadIdx.x; i < R2; i += 256) cur[i] = ob[i];
    __syncthreads();
    int beg = pb * RCHUNK;
    int end = beg + RCHUNK; if (end > R2E) end = R2E;
    for (int i = beg + threadIdx.x; i < end; i += 256) {
        int p = atomicAdd(&cur[s[i]], 1);
        o[p] = v[i];
    }
}

// ---------------- batched scatters (entity + super CSR; low contention) ----------------
__global__ void scatter3_k(const int* __restrict__ dst, const int* __restrict__ src,
                           const int* __restrict__ et, int* __restrict__ cur,
                           int* __restrict__ psrc, int* __restrict__ pet,
                           int per_t, int stride, int total) {
    int i = blockIdx.x * 256 + threadIdx.x;
    if (i < total) {
        int t = i / per_t;
        int p = atomicAdd(&cur[t * stride + dst[i]], 1);
        psrc[(size_t)t * per_t + p] = src[i];
        pet[(size_t)t * per_t + p] = et[i];
    }
}

// ---------------- block-aggregated zero-indeg list (1 atomic per block) ----------------
__global__ __launch_bounds__(256) void zlist3b_k(const int* __restrict__ cnt, int* __restrict__ zl,
                                                 int* __restrict__ nz, int n, int bpt) {
    int t = blockIdx.x / bpt;
    int pb = blockIdx.x - t * bpt;
    int i = pb * 256 + threadIdx.x;
    bool z = (i < n) && (cnt[(size_t)t * n + i] == 0);
    unsigned long long mask = __ballot(z);
    int wave = threadIdx.x >> 6, lane = threadIdx.x & 63;
    __shared__ int wbase[4];
    __shared__ int bbase;
    if (lane == 0) wbase[wave] = __popcll(mask);
    __syncthreads();
    if (threadIdx.x == 0) {
        int s0 = wbase[0], s1 = wbase[1], s2 = wbase[2], s3 = wbase[3];
        int tot = s0 + s1 + s2 + s3;
        bbase = tot ? atomicAdd(&nz[t], tot) : 0;
        wbase[0] = 0; wbase[1] = s0; wbase[2] = s0 + s1; wbase[3] = s0 + s1 + s2;
    }
    __syncthreads();
    if (z) {
        int off = bbase + wbase[wave] + __popcll(mask & ((1ull << lane) - 1ull));
        zl[(size_t)t * n + off] = i;
    }
}

// ---------------- small segment sum (SR path), LDS col-chunked ----------------
#define SEG_CW 25
__global__ __launch_bounds__(256) void seg_acc_k(const float* __restrict__ hsrc,
                                                 const int* __restrict__ idx,
                                                 const int* __restrict__ seg, int n,
                                                 float* __restrict__ acc, int nseg) {
    __shared__ float lacc[500 * SEG_CW];
    int cg = blockIdx.x & 7;
    int pb = blockIdx.x >> 3;
    int NPB = gridDim.x >> 3;
    int t = threadIdx.x;
    for (int i = t; i < nseg * SEG_CW; i += 256) lacc[i] = 0.f;
    __syncthreads();
    int chunk = (n + NPB - 1) / NPB;
    int beg = pb * chunk;
    int end = beg + chunk; if (end > n) end = n;
    if (t < 250) {
        int il = t / SEG_CW;
        int c = t - il * SEG_CW;
        int col = cg * SEG_CW + c;
        for (int i = beg + il; i < end; i += 10) {
            int r = seg[i];
            int e = idx[i];
            atomicAdd(&lacc[r * SEG_CW + c], hsrc[(size_t)e * H + col]);
        }
    }
    __syncthreads();
    for (int i = t; i < nseg * SEG_CW; i += 256) {
        int r = i / SEG_CW, c = i - (i / SEG_CW) * SEG_CW;
        atomicAdd(&acc[(size_t)r * H + cg * SEG_CW + c], lacc[i]);
    }
}

__global__ void seg_div_k(float* __restrict__ acc, const int* __restrict__ cnt, int rows) {
    int i = blockIdx.x * blockDim.x + threadIdx.x;
    if (i < rows * H) {
        int c = cnt[i / H];
        acc[i] /= (float)(c > 0 ? c : 1);
    }
}

// ---------------- seg-mean partials: 4 blocks per segment, disjoint buffers (no atomics) ----------------
__global__ __launch_bounds__(256) void seg_mean_part_k(const u16* __restrict__ h,
                                                       const int* __restrict__ per,
                                                       const int* __restrict__ off,
                                                       float* __restrict__ xpart, int nseg) {
    int r = blockIdx.x >> 2;
    int p = blockIdx.x & 3;
    if (r >= nseg) return;
    int wv = threadIdx.x >> 6, lane = threadIdx.x & 63;
    int beg = off[r], end = off[r + 1];
    float a0 = 0.f, a1 = 0.f, a2 = 0.f, a3 = 0.f;
    for (int i = beg + p * 4 + wv; i < end; i += 16) {
        int e = per[i];
        if (lane < 50) {
            uint2 u = ((const uint2*)(h + (size_t)e * H))[lane];
            a0 += bf2f(u.x & 0xffff); a1 += bf2f(u.x >> 16);
            a2 += bf2f(u.y & 0xffff); a3 += bf2f(u.y >> 16);
        }
    }
    __shared__ float red[4][200];
    if (lane < 50) *(float4*)(&red[wv][lane * 4]) = make_float4(a0, a1, a2, a3);
    __syncthreads();
    int t = threadIdx.x;
    if (t < 200) {
        float s = red[0][t] + red[1][t] + red[2][t] + red[3][t];
        xpart[((size_t)p * nseg + r) * H + t] = s;
    }
}
__global__ void seg_fin_k(const float* __restrict__ xpart, const int* __restrict__ off,
                          float* __restrict__ acc, int nseg) {
    int i = blockIdx.x * 256 + threadIdx.x;
    if (i < nseg * H) {
        int r = i / H;
        size_t stride = (size_t)nseg * H;
        float s = xpart[i] + xpart[stride + i] + xpart[2 * stride + i] + xpart[3 * stride + i];
        int c = off[r + 1] - off[r];
        acc[i] = s / (float)(c > 0 ? c : 1);
    }
}

// ---------------- fused LSTM cell + l2norm of h and c ----------------
__global__ __launch_bounds__(256) void lstm_k(const float* __restrict__ x1, const float* __restrict__ x2,
                                              const float* __restrict__ hprev, const float* __restrict__ cprev,
                                              const float* __restrict__ Wih, const float* __restrict__ Whh,
                                              const float* __restrict__ bih, const float* __restrict__ bhh,
                                              float* __restrict__ hout, float* __restrict__ cout, int rows) {
    int r = blockIdx.x;
    if (r >= rows) return;
    __shared__ float xb[2 * H], hb[H], gb[4 * H], hv[H], cv[H];
    __shared__ float red[8];
    int t = threadIdx.x;
    for (int i = t; i < 2 * H; i += 256)
        xb[i] = (i < H) ? x1[(size_t)r * H + i] : x2[(size_t)r * H + i - H];
    if (t < H) hb[t] = hprev[(size_t)r * H + t];
    __syncthreads();
    for (int j = t; j < 4 * H; j += 256) {
        float s = bih[j] + bhh[j];
        const float* wi = Wih + (size_t)j * 2 * H;
        for (int k = 0; k < 2 * H; ++k) s += xb[k] * wi[k];
        const float* wh = Whh + (size_t)j * H;
        for (int k = 0; k < H; ++k) s += hb[k] * wh[k];
        gb[j] = s;
    }
    __syncthreads();
    if (t < H) {
        float ig = fsig(gb[t]);
        float fg = fsig(gb[H + t]);
        float gg = ftanh(gb[2 * H + t]);
        float og = fsig(gb[3 * H + t]);
        float c2 = fg * cprev[(size_t)r * H + t] + ig * gg;
        cv[t] = c2;
        hv[t] = og * ftanh(c2);
    }
    __syncthreads();
    float sh = 0.f, sc = 0.f;
    if (t < H) { sh = hv[t] * hv[t]; sc = cv[t] * cv[t]; }
    for (int o = 32; o > 0; o >>= 1) { sh += __shfl_down(sh, o); sc += __shfl_down(sc, o); }
    if ((t & 63) == 0) { red[t >> 6] = sh; red[4 + (t >> 6)] = sc; }
    __syncthreads();
    if (t == 0) {
        red[0] = 1.f / fmaxf(sqrtf(red[0] + red[1] + red[2] + red[3]), 1e-12f);
        red[4] = 1.f / fmaxf(sqrtf(red[4] + red[5] + red[6] + red[7]), 1e-12f);
    }
    __syncthreads();
    if (t < H) {
        hout[(size_t)r * H + t] = hv[t] * red[0];
        cout[(size_t)r * H + t] = cv[t] * red[4];
    }
}

// ---------------- fused small GRU + l2norm (+bf16 mirror) ----------------
__global__ __launch_bounds__(256) void gru_small_k(const float* __restrict__ x, const float* __restrict__ h,
                                                   const float* __restrict__ Wih, const float* __restrict__ Whh,
                                                   const float* __restrict__ bih, const float* __restrict__ bhh,
                                                   float* __restrict__ outp, u16* __restrict__ mirp, int rows) {
    int r = blockIdx.x;
    if (r >= rows) return;
    __shared__ float xb[H], hb[H], gi[3 * H], gh[3 * H], ov[H];
    __shared__ float red[4];
    int t = threadIdx.x;
    if (t < H) { xb[t] = x[(size_t)r * H + t]; hb[t] = h[(size_t)r * H + t]; }
    __syncthreads();
    for (int j = t; j < 3 * H; j += 256) {
        float si = bih[j], sh2 = bhh[j];
        const float* wi = Wih + (size_t)j * H;
        const float* wh = Whh + (size_t)j * H;
        for (int k = 0; k < H; ++k) { si += xb[k] * wi[k]; sh2 += hb[k] * wh[k]; }
        gi[j] = si; gh[j] = sh2;
    }
    __syncthreads();
    if (t < H) {
        float rr = fsig(gi[t] + gh[t]);
        float zz = fsig(gi[H + t] + gh[H + t]);
        float nn = ftanh(gi[2 * H + t] + rr * gh[2 * H + t]);
        ov[t] = (1.f - zz) * nn + zz * hb[t];
    }
    __syncthreads();
    float s = (t < H) ? ov[t] * ov[t] : 0.f;
    for (int o = 32; o > 0; o >>= 1) s += __shfl_down(s, o);
    if ((t & 63) == 0) red[t >> 6] = s;
    __syncthreads();
    if (t == 0) red[0] = 1.f / fmaxf(sqrtf(red[0] + red[1] + red[2] + red[3]), 1e-12f);
    __syncthreads();
    if (t < H) {
        float v = ov[t] * red[0];
        outp[(size_t)r * H + t] = v;
        mirp[(size_t)r * H + t] = f2bf(v);
    }
}

// ---------------- fused super-graph layer: gather + rrelu(agg@Wn + cur@Wsel) ----------------
__global__ __launch_bounds__(256) void sup_fused_k(const float* __restrict__ cur, const float* __restrict__ prel,
                                                   const int* __restrict__ soff, const int* __restrict__ sssrc,
                                                   const int* __restrict__ sset,
                                                   const float* __restrict__ Wn, const float* __restrict__ We,
                                                   const float* __restrict__ Wl, const int* __restrict__ indeg,
                                                   float* __restrict__ outp) {
    int r = blockIdx.x;
    __shared__ float ar[H], cr[H];
    int t = threadIdx.x;
    if (t < H) {
        int beg = soff[r], end = soff[r + 1];
        float acc = 0.f;
        for (int i = beg; i < end; ++i)
            acc += cur[(size_t)sssrc[i] * H + t] + prel[(size_t)sset[i] * H + t];
        ar[t] = acc;
        cr[t] = cur[(size_t)r * H + t];
    }
    __syncthreads();
    const float* W2 = (indeg[r] > 0) ? We : Wl;
    if (t < H) {
        float s = 0.f;
        for (int k = 0; k < H; ++k) s += ar[k] * Wn[(size_t)k * H + t] + cr[k] * W2[(size_t)k * H + t];
        outp[(size_t)r * H + t] = (s >= 0.f) ? s : s * SLOPE;
    }
}

// ---------------- entity message aggregation via CSR (wave per dst), 2-edge unrolled ----------------
__global__ __launch_bounds__(256) void ent_agg_b_k(const u16* __restrict__ cur, const u16* __restrict__ rel,
                                                   const int* __restrict__ eoff, const int* __restrict__ esrc,
                                                   const int* __restrict__ eet, u16* __restrict__ agg, int n) {
    int wave = threadIdx.x >> 6, lane = threadIdx.x & 63;
    int v = blockIdx.x * 4 + wave;
    if (v >= n) return;
    float a0 = 0.f, a1 = 0.f, a2 = 0.f, a3 = 0.f;
    bool act = lane < 50;
    int beg = eoff[v], end = eoff[v + 1];
    int i = beg;
    for (; i + 2 <= end; i += 2) {
        int e0 = esrc[i], t0 = eet[i];
        int e1 = esrc[i + 1], t1 = eet[i + 1];
        if (act) {
            uint2 h0 = ((const uint2*)(cur + (size_t)e0 * H))[lane];
            uint2 h1 = ((const uint2*)(cur + (size_t)e1 * H))[lane];
            uint2 r0 = ((const uint2*)(rel + (size_t)t0 * H))[lane];
            uint2 r1 = ((const uint2*)(rel + (size_t)t1 * H))[lane];
            a0 += bf2f(h0.x & 0xffff) + bf2f(r0.x & 0xffff) + bf2f(h1.x & 0xffff) + bf2f(r1.x & 0xffff);
            a1 += bf2f(h0.x >> 16) + bf2f(r0.x >> 16) + bf2f(h1.x >> 16) + bf2f(r1.x >> 16);
            a2 += bf2f(h0.y & 0xffff) + bf2f(r0.y & 0xffff) + bf2f(h1.y & 0xffff) + bf2f(r1.y & 0xffff);
            a3 += bf2f(h0.y >> 16) + bf2f(r0.y >> 16) + bf2f(h1.y >> 16) + bf2f(r1.y >> 16);
        }
    }
    if (i < end) {
        int e0 = esrc[i], t0 = eet[i];
        if (act) {
            uint2 h0 = ((const uint2*)(cur + (size_t)e0 * H))[lane];
            uint2 r0 = ((const uint2*)(rel + (size_t)t0 * H))[lane];
            a0 += bf2f(h0.x & 0xffff) + bf2f(r0.x & 0xffff);
            a1 += bf2f(h0.x >> 16) + bf2f(r0.x >> 16);
            a2 += bf2f(h0.y & 0xffff) + bf2f(r0.y & 0xffff);
            a3 += bf2f(h0.y >> 16) + bf2f(r0.y >> 16);
        }
    }
    if (act) {
        uint2 o; o.x = pk2(a0, a1); o.y = pk2(a2, a3);
        ((uint2*)(agg + (size_t)v * H))[lane] = o;
    }
}

// ---------------- B-persistent bf16 MFMA GEMM, split-k B staging + partial last col group ----------------
#define BSTR 108   // padded LDS row stride
__global__ __launch_bounds__(128) void gemm_bp_k(const u16* __restrict__ A1, const u16* __restrict__ A2,
                                                 const u16* __restrict__ B1, const u16* __restrict__ B2,
                                                 u16* __restrict__ Cm, int M, int Nc) {
    __shared__ __bf16 Bs[64 * BSTR];  // 13824 B
    const int tid = threadIdx.x;
    int idx2 = xcd_swz(blockIdx.x, gridDim.x);
    const int m0 = (idx2 >> 2) * 128;
    const int n0 = (idx2 & 3) * 64;
    const int nfb = (n0 + 16 >= Nc) ? 1 : 4;        // last col group: only 1 useful 16-col frag
    const int brows = (nfb == 1) ? 16 : 64;
    const int w = tid >> 6, lane = tid & 63;
    const int lr = lane & 15, lo = lane >> 4;
    const int mbase = m0 + w * 64;

    bf8 zb;
#pragma unroll
    for (int e = 0; e < 8; ++e) zb[e] = (__bf16)0.f;

    f32x4 acc[4][4];
#pragma unroll
    for (int i = 0; i < 4; ++i)
#pragma unroll
        for (int j = 0; j < 4; ++j)
#pragma unroll
            for (int e = 0; e < 4; ++e) acc[i][j][e] = 0.f;

    auto stageB = [&](const u16* Bp, int kbase, int nch) {
        for (int ch = tid; ch < brows * nch; ch += 128) {
            int n = ch / nch, q = ch - n * nch;
            int ng = n0 + n;
            uint4 v = make_uint4(0, 0, 0, 0);
            if (ng < Nc) v = *(const uint4*)(Bp + (size_t)ng * 200 + kbase + q * 8);
            *(uint4*)(&Bs[n * BSTR + q * 8]) = v;
        }
    };
    auto loadA = [&](bf8* buf, const u16* Ap, int kt7) {
        int kk = kt7 * 32 + lo * 8;
        bool kv = kk < 200;
#pragma unroll
        for (int mf = 0; mf < 4; ++mf) {
            int m = mbase + mf * 16 + lr;
            bf8 v = zb;
            if (kv && m < M) v = *(const bf8*)(Ap + (size_t)m * 200 + kk);
            buf[mf] = v;
        }
    };
    auto mmaStep = [&](bf8* a, int kt7, int kbase) {
        int kk = kt7 * 32 + lo * 8;
        int kcl = (kk < 200) ? (kk - kbase) : 0;
#pragma unroll
        for (int nf = 0; nf < 4; ++nf) {
            if (nf < nfb) {
                bf8 b = *(const bf8*)(&Bs[(nf * 16 + lr) * BSTR + kcl]);
#pragma unroll
                for (int mf = 0; mf < 4; ++mf)
                    acc[mf][nf] = __builtin_amdgcn_mfma_f32_16x16x32_bf16(a[mf], b, acc[mf][nf], 0, 0, 0);
            }
        }
    };

    bf8 a0[4], a1[4];
    stageB(B1, 0, 12);
    __syncthreads();
    loadA(a0, A1, 0);
    loadA(a1, A1, 1); mmaStep(a0, 0, 0);
    loadA(a0, A1, 2); mmaStep(a1, 1, 0);
    loadA(a1, A1, 3); mmaStep(a0, 2, 0);
    __syncthreads();
    stageB(B1, 96, 13);
    __syncthreads();
    loadA(a0, A1, 4); mmaStep(a1, 3, 96);
    loadA(a1, A1, 5); mmaStep(a0, 4, 96);
    loadA(a0, A1, 6); mmaStep(a1, 5, 96);
    loadA(a1, A2, 0); mmaStep(a0, 6, 96);
    __syncthreads();
    stageB(B2, 0, 12);
    __syncthreads();
    loadA(a0, A2, 1); mmaStep(a1, 0, 0);
    loadA(a1, A2, 2); mmaStep(a0, 1, 0);
    loadA(a0, A2, 3); mmaStep(a1, 2, 0);
    __syncthreads();
    stageB(B2, 96, 13);
    __syncthreads();
    loadA(a1, A2, 4); mmaStep(a0, 3, 96);
    loadA(a0, A2, 5); mmaStep(a1, 4, 96);
    loadA(a1, A2, 6); mmaStep(a0, 5, 96);
    mmaStep(a1, 6, 96);

#pragma unroll
    for (int mf = 0; mf < 4; ++mf) {
#pragma unroll
        for (int r = 0; r < 4; ++r) {
            int m = mbase + mf * 16 + lo * 4 + r;
            if (m >= M) continue;
#pragma unroll
            for (int nf = 0; nf < 4; ++nf) {
                if (nf >= nfb) continue;
                int n = n0 + nf * 16 + lr;
                if (n >= Nc) continue;
                float v = acc[mf][nf][r];
                v = (v >= 0.f) ? v : v * SLOPE;
                Cm[(size_t)m * Nc + n] = f2bf(v);
            }
        }
    }
}

// ---------------- fixup for zero-indeg rows: out[row] = rrelu(h[row] @ Wl), bf16 io ----------------
__global__ __launch_bounds__(256) void fixup_b_k(const u16* __restrict__ h, const float* __restrict__ Wl,
                                                 const int* __restrict__ zl, const int* __restrict__ nz,
                                                 u16* __restrict__ outp) {
    __shared__ float xr[H];
    int nzv = *nz;
    for (int z = blockIdx.x; z < nzv; z += gridDim.x) {
        int row = zl[z];
        if (threadIdx.x < H) xr[threadIdx.x] = bf2f(h[(size_t)row * H + threadIdx.x]);
        __syncthreads();
        if (threadIdx.x < H) {
            float s = 0.f;
            for (int k = 0; k < H; ++k) s += xr[k] * Wl[(size_t)k * H + threadIdx.x];
            outp[(size_t)row * H + threadIdx.x] = f2bf((s >= 0.f) ? s : s * SLOPE);
        }
        __syncthreads();
    }
}

// ---------------- W-in-LDS entity GRU: padded LDS (204), bf16 h for z*h, bf16 out ----------------
#define GCG2 13       // col groups of 16
#define GTPB 6        // row tiles (128 rows each) per block
#define WSTR 204      // padded Ws row stride
__global__ __launch_bounds__(256, 4) void gru_wlds_k(const u16* __restrict__ Xb, const u16* __restrict__ Hb,
                                                     const u16* __restrict__ Wb,
                                                     const float* __restrict__ bih, const float* __restrict__ bhh,
                                                     u16* __restrict__ Outb, int M) {
    __shared__ __bf16 Ws[6][16 * WSTR];   // 39168 B
    const int tid = threadIdx.x;
    int idx2 = xcd_swz(blockIdx.x, gridDim.x);
    const int cg = idx2 % GCG2;
    const int rb = idx2 / GCG2;
    const int w = tid >> 6, lane = tid & 63;
    const int lr = lane & 15, lo = lane >> 4;
    const int c0 = cg * 16;

    for (int ch = tid; ch < 2400; ch += 256) {
        int s = ch / 400;
        int rem = ch - s * 400;
        int col = rem / 25, q = rem - (rem / 25) * 25;
        int cc = c0 + col; if (cc > 199) cc = 199;
        uint4 v = *(const uint4*)(Wb + (size_t)(s * 200 + cc) * 200 + q * 8);
        *(uint4*)(&Ws[s][col * WSTR + q * 8]) = v;
    }
    __syncthreads();

    int c = c0 + lr;
    const bool cvalid = c < 200;
    const int cc = cvalid ? c : 199;
    const float b0 = bih[cc], b1 = bih[200 + cc], b2 = bih[400 + cc];
    const float b3 = bhh[cc], b4 = bhh[200 + cc], b5 = bhh[400 + cc];

    bf8 zb;
#pragma unroll
    for (int e = 0; e < 8; ++e) zb[e] = (__bf16)0.f;

    for (int tile = 0; tile < GTPB; ++tile) {
        int mbase = (rb * GTPB + tile) * 128 + w * 32;
        if (mbase >= M) break;
        int m0r = mbase + lr;      if (m0r >= M) m0r = M - 1;
        int m1r = mbase + 16 + lr; if (m1r >= M) m1r = M - 1;
        const u16* Xp0 = Xb + (size_t)m0r * 200 + lo * 8;
        const u16* Xp1 = Xb + (size_t)m1r * 200 + lo * 8;
        const u16* Hp0 = Hb + (size_t)m0r * 200 + lo * 8;
        const u16* Hp1 = Hb + (size_t)m1r * 200 + lo * 8;

        f32x4 acc[6][2];
#pragma unroll
        for (int s = 0; s < 6; ++s)
#pragma unroll
            for (int i = 0; i < 2; ++i)
#pragma unroll
                for (int e = 0; e < 4; ++e) acc[s][i][e] = 0.f;

#pragma unroll
        for (int kt = 0; kt < 7; ++kt) {
            const int koff = kt * 32;
            const bool kv = (kt < 6) || (lo == 0);
            const int kcl = kv ? (koff + lo * 8) : 0;
            bf8 xa0 = zb, xa1 = zb, ha0 = zb, ha1 = zb;
            if (kv) {
                xa0 = *(const bf8*)(Xp0 + koff);
                xa1 = *(const bf8*)(Xp1 + koff);
                ha0 = *(const bf8*)(Hp0 + koff);
                ha1 = *(const bf8*)(Hp1 + koff);
            }
#pragma unroll
            for (int s = 0; s < 6; ++s) {
                bf8 wv = *(const bf8*)(&Ws[s][lr * WSTR + kcl]);
                bf8 a0f = (s < 3) ? xa0 : ha0;
                bf8 a1f = (s < 3) ? xa1 : ha1;
                acc[s][0] = __builtin_amdgcn_mfma_f32_16x16x32_bf16(a0f, wv, acc[s][0], 0, 0, 0);
                acc[s][1] = __builtin_amdgcn_mfma_f32_16x16x32_bf16(a1f, wv, acc[s][1], 0, 0, 0);
            }
        }
        if (cvalid) {
#pragma unroll
            for (int mf = 0; mf < 2; ++mf) {
#pragma unroll
                for (int r = 0; r < 4; ++r) {
                    int m = mbase + mf * 16 + lo * 4 + r;
                    if (m >= M) continue;
                    float ir = acc[0][mf][r] + b0;
                    float iz = acc[1][mf][r] + b1;
                    float in_ = acc[2][mf][r] + b2;
                    float hr = acc[3][mf][r] + b3;
                    float hz = acc[4][mf][r] + b4;
                    float hn = acc[5][mf][r] + b5;
                    float rr = fsig(ir + hr);
                    float zz = fsig(iz + hz);
                    float nn = ftanh(in_ + rr * hn);
                    float hvv = bf2f(Hb[(size_t)m * 200 + c]);
                    Outb[(size_t)m * 200 + c] = f2bf((1.f - zz) * nn + zz * hvv);
                }
            }
        }
    }
}

// =========================== host orchestration ===========================
extern "C" void kernel_launch(void* const* d_in, const int* in_sizes, int n_in,
                              void* d_out, int out_size, void* d_ws, size_t ws_size,
                              hipStream_t stream) {
    (void)in_sizes; (void)n_in; (void)out_size; (void)ws_size;
    const int* src  = (const int*)d_in[0];
    const int* dst  = (const int*)d_in[1];
    const int* etyp = (const int*)d_in[2];
    const int* rte  = (const int*)d_in[3];
    const int* rseg = (const int*)d_in[4];
    const int* ssrc = (const int*)d_in[5];
    const int* sdst = (const int*)d_in[6];
    const int* setp = (const int*)d_in[7];
    const int* srte = (const int*)d_in[8];
    const int* srseg= (const int*)d_in[9];
    const float* dyn     = (const float*)d_in[10];
    const float* emb_rel = (const float*)d_in[11];
    const float* p_rel   = (const float*)d_in[12];
    const float* Wih1 = (const float*)d_in[13]; const float* Whh1 = (const float*)d_in[14];
    const float* bih1 = (const float*)d_in[15]; const float* bhh1 = (const float*)d_in[16];
    const float* Wih2 = (const float*)d_in[17]; const float* Whh2 = (const float*)d_in[18];
    const float* bih2 = (const float*)d_in[19]; const float* bhh2 = (const float*)d_in[20];
    const float* Wih3 = (const float*)d_in[21]; const float* Whh3 = (const float*)d_in[22];
    const float* bih3 = (const float*)d_in[23]; const float* bhh3 = (const float*)d_in[24];
    const float* Wihe = (const float*)d_in[25]; const float* Whhe = (const float*)d_in[26];
    const float* bihe = (const float*)d_in[27]; const float* bhhe = (const float*)d_in[28];
    const float* Wn  = (const float*)d_in[29];
    const float* Wl  = (const float*)d_in[30];
    const float* We  = (const float*)d_in[31];
    const float* sWn = (const float*)d_in[32];
    const float* sWl = (const float*)d_in[33];
    const float* sWe = (const float*)d_in[34];

    float* out = (float*)d_out;
    const size_t NH = (size_t)N_NODES * H;
    float* relout = out + 3 * NH;

    char* wp = (char*)d_ws;
    auto carve = [&](size_t bytes) -> void* {
        void* p = (void*)wp;
        wp += (bytes + 255) & ~(size_t)255;
        return p;
    };
    u16* aggB = (u16*)carve(NH * 2);
    u16* m0b  = (u16*)carve(NH * 2);
    u16* m1b  = (u16*)carve(NH * 2);
    u16* hmir = (u16*)carve(NH * 2);
    u16* gob  = (u16*)carve(NH * 2);   // bf16 GRU output
    u16* relm = (u16*)carve((size_t)R2 * H * 2);
    u16* wtB  = (u16*)carve((size_t)400000 * 2);
    float* h0a  = (float*)carve((size_t)R2 * H * 4);
    float* c0b  = (float*)carve((size_t)R2 * H * 4);
    float* xin  = (float*)carve((size_t)R2 * H * 4);
    float* xpart= (float*)carve((size_t)4 * R2 * H * 4);
    float* srelA= (float*)carve((size_t)R2 * H * 4);
    float* srelB= (float*)carve((size_t)R2 * H * 4);
    float* sxin = (float*)carve((size_t)SR * H * 4);
    float* p_h  = (float*)carve((size_t)SR * H * 4);
    float* p_c  = (float*)carve((size_t)SR * H * 4);
    // persistent (used inside t-loop) batched CSR data
    int* eoff3  = (int*)carve((size_t)3 * (N_NODES + 1) * 4);
    int* esrcp3 = (int*)carve((size_t)3 * E_EDGES * 4);
    int* eetp3  = (int*)carve((size_t)3 * E_EDGES * 4);
    int* zl3    = (int*)carve((size_t)3 * N_NODES * 4);
    int* nz3    = (int*)carve(3 * 4);
    int* rcsr3  = (int*)carve((size_t)3 * (R2 + 1) * 4);
    int* rper3  = (int*)carve((size_t)3 * R2E * 4);
    int* sindeg3= (int*)carve((size_t)3 * R2 * 4);
    int* scnt3  = (int*)carve((size_t)3 * SR * 4);
    int* hist3  = (int*)carve((size_t)3 * NB * R2 * 4);
    int* offb3  = (int*)carve((size_t)3 * NB * R2 * 4);
    int* soff3  = (int*)carve((size_t)3 * (R2 + 1) * 4);
    int* scur3  = (int*)carve((size_t)3 * R2 * 4);
    int* sssrc3 = (int*)carve((size_t)3 * SE_EDGES * 4);
    int* sset3  = (int*)carve((size_t)3 * SE_EDGES * 4);
    int* bsum3  = (int*)carve((size_t)3 * NCH * 4);
    int* boff3  = (int*)carve((size_t)3 * NCH * 4);
    // transient (pre-loop only) arrays aliased into loop-phase buffers
    int* ecnt3 = (int*)m0b;
    int* rcnt3 = (int*)m0b + 3 * N_NODES;
    int* ecur3 = (int*)aggB;
    int* rcur3 = (int*)aggB + 3 * N_NODES;

    // ---- weights -> bf16 ----
    dim3 wg4(157, 4);
    wconv4_k<<<wg4, 256, 0, stream>>>(Wn, We, Wn + 40000, We + 40000, wtB);
    wconv2_k<<<938, 256, 0, stream>>>(Wihe, Whhe, wtB + 160000);

    // ---- batched graph preprocessing ----
    hipMemsetAsync(ecnt3, 0, (size_t)3 * N_NODES * 4, stream);
    hipMemsetAsync(rcnt3, 0, (size_t)3 * R2 * 4, stream);
    hipMemsetAsync(nz3, 0, 3 * 4, stream);
    hipMemsetAsync(sindeg3, 0, (size_t)3 * R2 * 4, stream);
    hipMemsetAsync(scnt3, 0, (size_t)3 * SR * 4, stream);
    cnt3_k<<<(3 * E_EDGES + 255) / 256, 256, 0, stream>>>(dst, 3 * E_EDGES, E_EDGES, N_NODES, ecnt3);
    scanA_k<<<3 * NCH, 256, 0, stream>>>(ecnt3, bsum3, N_NODES);
    scanB_k<<<3, 128, 0, stream>>>(bsum3, boff3, eoff3, N_NODES);
    scanC_k<<<3 * NCH, 256, 0, stream>>>(ecnt3, boff3, eoff3, ecur3, N_NODES);
    scatter3_k<<<(3 * E_EDGES + 255) / 256, 256, 0, stream>>>(dst, src, etyp, ecur3, esrcp3, eetp3,
                                                             E_EDGES, N_NODES, 3 * E_EDGES);
    {
        int bpt = (N_NODES + 255) / 256;
        zlist3b_k<<<3 * bpt, 256, 0, stream>>>(ecnt3, zl3, nz3, N_NODES, bpt);
    }
    hist3_k<<<3 * NB, 256, 0, stream>>>(rseg, hist3, rcnt3);
    scan3_k<<<3, 1024, 0, stream>>>(rcnt3, rcsr3, rcur3, R2);
    offs3_k<<<3 * R2, 64, 0, stream>>>(hist3, rcsr3, offb3);
    part3_k<<<3 * NB, 256, 0, stream>>>(rseg, rte, offb3, rper3);
    seg_cnt3_k<<<12, 256, 0, stream>>>(srseg, S2E, SR, 4, scnt3);
    cnt3_k<<<(3 * SE_EDGES + 255) / 256, 256, 0, stream>>>(sdst, 3 * SE_EDGES, SE_EDGES, R2, sindeg3);
    scan3_k<<<3, 1024, 0, stream>>>(sindeg3, soff3, scur3, R2);
    scatter3_k<<<(3 * SE_EDGES + 255) / 256, 256, 0, stream>>>(sdst, ssrc, setp, scur3, sssrc3, sset3,
                                                              SE_EDGES, R2, 3 * SE_EDGES);

    // h = l2norm(dynamic_emb) -> out+NH (scratch fp32) + hmir
    l2norm_k<<<(N_NODES + 3) / 4, 256, 0, stream>>>(dyn, out + NH, hmir, N_NODES);

    const int gw  = 4 * ((N_NODES + 127) / 128);                       // 3128 blocks of 128 thr
    const int NRB2 = (N_NODES + GTPB * 128 - 1) / (GTPB * 128);        // 131
    const int gwg = GCG2 * NRB2;                                       // 1703 blocks of 256 thr

    for (int t = 0; t < T_STEPS; ++t) {
        const int* srte_t = srte + (size_t)t * S2E;
        const int* srseg_t= srseg + (size_t)t * S2E;
        const int* eoff_t = eoff3 + (size_t)t * (N_NODES + 1);
        const int* esrc_t = esrcp3 + (size_t)t * E_EDGES;
        const int* eet_t  = eetp3 + (size_t)t * E_EDGES;
        const int* zl_t   = zl3 + (size_t)t * N_NODES;
        const int* nz_t   = nz3 + t;
        const int* rcsr_t = rcsr3 + (size_t)t * (R2 + 1);
        const int* rper_t = rper3 + (size_t)t * R2E;
        const int* sind_t = sindeg3 + (size_t)t * R2;
        const int* scnt_t = scnt3 + (size_t)t * SR;
        const int* soff_t = soff3 + (size_t)t * (R2 + 1);
        const int* sssrc_t= sssrc3 + (size_t)t * SE_EDGES;
        const int* sset_t = sset3 + (size_t)t * SE_EDGES;

        float* hist = out + (size_t)t * NH;
        float* rel_t = relout + (size_t)t * R2 * H;
        const float* hprev = (t == 0) ? emb_rel : relout + (size_t)(t - 1) * R2 * H;
        const float* cprev = (t == 0) ? xin : c0b;
        const float* php   = (t == 0) ? p_rel : p_h;
        const float* pcp   = (t == 0) ? sxin : p_c;

        // ---- x_input = seg_mean(h[r_to_e], r_seg, R2): 4-way disjoint partials + finalize ----
        seg_mean_part_k<<<R2 * 4, 256, 0, stream>>>(hmir, rper_t, rcsr_t, xpart, R2);
        seg_fin_k<<<(R2 * H + 255) / 256, 256, 0, stream>>>(xpart, rcsr_t, xin, R2);
        // ---- LSTM1 ----
        lstm_k<<<R2, 256, 0, stream>>>(emb_rel, xin, hprev, cprev, Wih1, Whh1, bih1, bhh1, h0a, c0b, R2);
        // ---- sx = seg_mean(h_0[s_r_to_e], s_r_seg, SR) ----
        hipMemsetAsync(sxin, 0, (size_t)SR * H * 4, stream);
        seg_acc_k<<<16 * 8, 256, 0, stream>>>(h0a, srte_t, srseg_t, S2E, sxin, SR);
        seg_div_k<<<(SR * H + 255) / 256, 256, 0, stream>>>(sxin, scnt_t, SR);
        // ---- LSTM2 ----
        lstm_k<<<SR, 256, 0, stream>>>(p_rel, sxin, php, pcp, Wih2, Whh2, bih2, bhh2, p_h, p_c, SR);
        // ---- super RGCN (2 fused layers) ----
        sup_fused_k<<<R2, 256, 0, stream>>>(h0a, p_h, soff_t, sssrc_t, sset_t, sWn, sWe, sWl, sind_t, srelA);
        sup_fused_k<<<R2, 256, 0, stream>>>(srelA, p_h, soff_t, sssrc_t, sset_t,
                                            sWn + H * H, sWe + H * H, sWl + H * H, sind_t, srelB);
        l2norm_k<<<(R2 + 3) / 4, 256, 0, stream>>>(srelB, srelB, (u16*)nullptr, R2);
        // ---- rel GRU -> rel_embs[t] (+bf16 mirror) ----
        gru_small_k<<<R2, 256, 0, stream>>>(srelB, h0a, Wih3, Whh3, bih3, bhh3, rel_t, relm, R2);

        // ---- entity layer 0 (bf16 in, bf16 out) ----
        ent_agg_b_k<<<(N_NODES + 3) / 4, 256, 0, stream>>>(hmir, relm, eoff_t, esrc_t, eet_t, aggB, N_NODES);
        gemm_bp_k<<<gw, 128, 0, stream>>>(aggB, hmir, wtB, wtB + 40000, m0b, N_NODES, H);
        fixup_b_k<<<2048, 256, 0, stream>>>(hmir, Wl, zl_t, nz_t, m0b);
        // ---- entity layer 1 ----
        ent_agg_b_k<<<(N_NODES + 3) / 4, 256, 0, stream>>>(m0b, relm, eoff_t, esrc_t, eet_t, aggB, N_NODES);
        gemm_bp_k<<<gw, 128, 0, stream>>>(aggB, m0b, wtB + 80000, wtB + 120000, m1b, N_NODES, H);
        fixup_b_k<<<2048, 256, 0, stream>>>(m0b, Wl + H * H, zl_t, nz_t, m1b);
        l2norm_b_k<<<(N_NODES + 3) / 4, 256, 0, stream>>>(m1b, N_NODES);

        // ---- W-in-LDS entity GRU (bf16 out) -> l2norm to fp32 hist + hmir ----
        gru_wlds_k<<<gwg, 256, 0, stream>>>(m1b, hmir, wtB + 160000, bihe, bhhe, gob, N_NODES);
        l2norm_bb_k<<<(N_NODES + 3) / 4, 256, 0, stream>>>(gob, hist, hmir, N_NODES);
    }
}

// Round 18
// 2551.276 us; speedup vs baseline: 1.4079x; 1.0042x over previous
//
#include <hip/hip_runtime.h>
#include <math.h>

#define N_NODES 100000
#define H 200
#define R2 500
#define T_STEPS 3
#define E_EDGES 300000
#define R2E 400000
#define SE_EDGES 4000
#define SR 8
#define S2E 8000
#define SLOPE 0.22916666666666666f
#define NB 64            // partition blocks per timestep for r_seg
#define RCHUNK ((R2E + NB - 1) / NB)
#define NCH 128          // chunks per timestep for entity CSR scan
#define CHSZ ((N_NODES + NCH - 1) / NCH)   // 782
#define SPT  ((CHSZ + 255) / 256)          // 4 elems per thread in scan phases

typedef unsigned short u16;
typedef unsigned int u32;
typedef __bf16 bf8 __attribute__((ext_vector_type(8)));
typedef float f32x4 __attribute__((ext_vector_type(4)));

static __device__ __forceinline__ float fsig(float x) { return 1.f / (1.f + __expf(-x)); }
static __device__ __forceinline__ float ftanh(float x) {
    float e = __expf(-2.f * fabsf(x));
    float t = (1.f - e) / (1.f + e);
    return (x >= 0.f) ? t : -t;
}
static __device__ __forceinline__ float bf2f(u32 lo16) {
    u32 v = lo16 << 16; float f; __builtin_memcpy(&f, &v, 4); return f;
}
static __device__ __forceinline__ u16 f2bf(float a) {
    __bf16 x = (__bf16)a; u16 u; __builtin_memcpy(&u, &x, 2); return u;
}
static __device__ __forceinline__ u32 pk2(float a, float b) {
    return (u32)f2bf(a) | ((u32)f2bf(b) << 16);
}
// bijective XCD swizzle (m204)
static __device__ __forceinline__ int xcd_swz(int b, int nwg) {
    int q = nwg >> 3, r = nwg & 7;
    int xcd = b & 7, u = b >> 3;
    int start = xcd * q + (xcd < r ? xcd : r);
    return start + u;
}

// ---------------- l2 normalize rows fp32 (+optional bf16 mirror); src may alias dst ----------------
__global__ __launch_bounds__(256) void l2norm_k(const float* __restrict__ src, float* __restrict__ dst,
                                                u16* __restrict__ mir, int rows) {
    int wave = threadIdx.x >> 6, lane = threadIdx.x & 63;
    int r = blockIdx.x * 4 + wave;
    if (r >= rows) return;
    float4 v = make_float4(0.f, 0.f, 0.f, 0.f);
    if (lane < 50) v = *(const float4*)(src + (size_t)r * H + lane * 4);
    float s = v.x * v.x + v.y * v.y + v.z * v.z + v.w * v.w;
    for (int o = 32; o > 0; o >>= 1) s += __shfl_down(s, o);
    float rn = 1.f / fmaxf(sqrtf(__shfl(s, 0)), 1e-12f);
    if (lane < 50) {
        float4 o4 = make_float4(v.x * rn, v.y * rn, v.z * rn, v.w * rn);
        *(float4*)(dst + (size_t)r * H + lane * 4) = o4;
        if (mir) {
            uint2 u; u.x = pk2(o4.x, o4.y); u.y = pk2(o4.z, o4.w);
            *(uint2*)(mir + (size_t)r * H + lane * 4) = u;
        }
    }
}

// ---------------- l2 normalize bf16 rows in place ----------------
__global__ __launch_bounds__(256) void l2norm_b_k(u16* __restrict__ buf, int rows) {
    int wave = threadIdx.x >> 6, lane = threadIdx.x & 63;
    int r = blockIdx.x * 4 + wave;
    if (r >= rows) return;
    uint2 u = make_uint2(0, 0);
    if (lane < 50) u = *(const uint2*)(buf + (size_t)r * H + lane * 4);
    float x0 = bf2f(u.x & 0xffff), x1 = bf2f(u.x >> 16);
    float x2 = bf2f(u.y & 0xffff), x3 = bf2f(u.y >> 16);
    float s = x0 * x0 + x1 * x1 + x2 * x2 + x3 * x3;
    for (int o = 32; o > 0; o >>= 1) s += __shfl_down(s, o);
    float rn = 1.f / fmaxf(sqrtf(__shfl(s, 0)), 1e-12f);
    if (lane < 50) {
        uint2 o2; o2.x = pk2(x0 * rn, x1 * rn); o2.y = pk2(x2 * rn, x3 * rn);
        *(uint2*)(buf + (size_t)r * H + lane * 4) = o2;
    }
}

// ---------------- l2 normalize bf16 src -> fp32 dst + bf16 mirror ----------------
__global__ __launch_bounds__(256) void l2norm_bb_k(const u16* __restrict__ src, float* __restrict__ dst,
                                                   u16* __restrict__ mir, int rows) {
    int wave = threadIdx.x >> 6, lane = threadIdx.x & 63;
    int r = blockIdx.x * 4 + wave;
    if (r >= rows) return;
    uint2 u = make_uint2(0, 0);
    if (lane < 50) u = *(const uint2*)(src + (size_t)r * H + lane * 4);
    float x0 = bf2f(u.x & 0xffff), x1 = bf2f(u.x >> 16);
    float x2 = bf2f(u.y & 0xffff), x3 = bf2f(u.y >> 16);
    float s = x0 * x0 + x1 * x1 + x2 * x2 + x3 * x3;
    for (int o = 32; o > 0; o >>= 1) s += __shfl_down(s, o);
    float rn = 1.f / fmaxf(sqrtf(__shfl(s, 0)), 1e-12f);
    if (lane < 50) {
        float4 o4 = make_float4(x0 * rn, x1 * rn, x2 * rn, x3 * rn);
        *(float4*)(dst + (size_t)r * H + lane * 4) = o4;
        uint2 o2; o2.x = pk2(o4.x, o4.y); o2.y = pk2(o4.z, o4.w);
        *(uint2*)(mir + (size_t)r * H + lane * 4) = o2;
    }
}

// ---------------- weight converts ----------------
__global__ void wconv4_k(const float* __restrict__ W0, const float* __restrict__ W1,
                         const float* __restrict__ W2, const float* __restrict__ W3,
                         u16* __restrict__ o) {
    int m = blockIdx.y;
    const float* W = (m == 0) ? W0 : (m == 1) ? W1 : (m == 2) ? W2 : W3;
    int i = blockIdx.x * 256 + threadIdx.x;
    if (i < 40000) { int n = i / 200, k = i - n * 200; o[m * 40000 + i] = f2bf(W[k * 200 + n]); }
}
__global__ void wconv2_k(const float* __restrict__ Wa, const float* __restrict__ Wb, u16* __restrict__ o) {
    int i = blockIdx.x * 256 + threadIdx.x;
    if (i < 240000) o[i] = f2bf(i < 120000 ? Wa[i] : Wb[i - 120000]);
}

// ---------------- batched counting over 3 timesteps ----------------
__global__ void cnt3_k(const int* __restrict__ d, int total, int per_t, int stride, int* __restrict__ cnt) {
    int i = blockIdx.x * 256 + threadIdx.x;
    if (i < total) { int t = i / per_t; atomicAdd(&cnt[t * stride + d[i]], 1); }
}

// ---------------- batched segment counts with LDS hierarchy ----------------
__global__ __launch_bounds__(256) void seg_cnt3_k(const int* __restrict__ seg, int per_t, int nseg,
                                                  int blocks_per_t, int* __restrict__ cnt) {
    __shared__ int lc[500];
    int t = blockIdx.x / blocks_per_t;
    int pb = blockIdx.x - t * blocks_per_t;
    const int* s = seg + (size_t)t * per_t;
    int* c = cnt + (size_t)t * nseg;
    for (int i = threadIdx.x; i < nseg; i += 256) lc[i] = 0;
    __syncthreads();
    int chunk = (per_t + blocks_per_t - 1) / blocks_per_t;
    int beg = pb * chunk;
    int end = beg + chunk; if (end > per_t) end = per_t;
    for (int i = beg + threadIdx.x; i < end; i += 256) atomicAdd(&lc[s[i]], 1);
    __syncthreads();
    for (int i = threadIdx.x; i < nseg; i += 256) if (lc[i]) atomicAdd(&c[i], lc[i]);
}

// ---------------- r_seg partition: per-block histogram + totals ----------------
__global__ __launch_bounds__(256) void hist3_k(const int* __restrict__ seg,
                                               int* __restrict__ hist, int* __restrict__ cnt) {
    __shared__ int lc[R2];
    int t = blockIdx.x / NB;
    int pb = blockIdx.x - t * NB;
    const int* s = seg + (size_t)t * R2E;
    for (int i = threadIdx.x; i < R2; i += 256) lc[i] = 0;
    __syncthreads();
    int beg = pb * RCHUNK;
    int end = beg + RCHUNK; if (end > R2E) end = R2E;
    for (int i = beg + threadIdx.x; i < end; i += 256) atomicAdd(&lc[s[i]], 1);
    __syncthreads();
    int* hrow = hist + (size_t)(t * NB + pb) * R2;
    int* c = cnt + (size_t)t * R2;
    for (int i = threadIdx.x; i < R2; i += 256) {
        hrow[i] = lc[i];
        if (lc[i]) atomicAdd(&c[i], lc[i]);
    }
}

// ---------------- small batched CSR scan (single block per t; for nseg<=1000) ----------------
__global__ __launch_bounds__(1024) void scan3_k(const int* __restrict__ cntA, int* __restrict__ offA,
                                                int* __restrict__ curA, int n) {
    const int b = blockIdx.x;
    const int* cnt = cntA + (size_t)b * n;
    int* off = offA + (size_t)b * (n + 1);
    int* cur = curA + (size_t)b * n;
    __shared__ int part[1024];
    int tid = threadIdx.x;
    int per = (n + 1023) / 1024;
    int s0 = tid * per;
    int e0 = s0 + per; if (e0 > n) e0 = n;
    int sum = 0;
    for (int i = s0; i < e0; ++i) sum += cnt[i];
    part[tid] = sum;
    __syncthreads();
    for (int d = 1; d < 1024; d <<= 1) {
        int v = (tid >= d) ? part[tid - d] : 0;
        __syncthreads();
        part[tid] += v;
        __syncthreads();
    }
    int excl = (tid == 0) ? 0 : part[tid - 1];
    for (int i = s0; i < e0; ++i) { off[i] = excl; cur[i] = excl; excl += cnt[i]; }
    if (tid == 1023) off[n] = excl;
}

// ---------------- multi-block entity CSR scan: phase A (chunk sums) ----------------
__global__ __launch_bounds__(256) void scanA_k(const int* __restrict__ cntA, int* __restrict__ bsum, int n) {
    int b = blockIdx.x;
    int t = b / NCH, ch = b - t * NCH;
    const int* cnt = cntA + (size_t)t * n;
    int base = ch * CHSZ;
    int cend = base + CHSZ; if (cend > n) cend = n;
    int s0 = base + threadIdx.x * SPT;
    int e0 = s0 + SPT; if (e0 > cend) e0 = cend;
    int sum = 0;
    for (int i = s0; i < e0 && i < cend; ++i) sum += cnt[i];
    __shared__ int red[256];
    red[threadIdx.x] = (s0 < cend) ? sum : 0;
    __syncthreads();
    for (int o = 128; o > 0; o >>= 1) {
        if (threadIdx.x < o) red[threadIdx.x] += red[threadIdx.x + o];
        __syncthreads();
    }
    if (threadIdx.x == 0) bsum[t * NCH + ch] = red[0];
}

// ---------------- phase B: exclusive scan of chunk sums per timestep (+ write off[n]) ----------------
__global__ __launch_bounds__(128) void scanB_k(const int* __restrict__ bsum, int* __restrict__ boff,
                                               int* __restrict__ offA, int n) {
    int t = blockIdx.x;
    int tid = threadIdx.x;  // 0..127
    __shared__ int part[128];
    int v = bsum[t * NCH + tid];
    part[tid] = v;
    __syncthreads();
    for (int d = 1; d < 128; d <<= 1) {
        int u = (tid >= d) ? part[tid - d] : 0;
        __syncthreads();
        part[tid] += u;
        __syncthreads();
    }
    boff[t * NCH + tid] = part[tid] - v;   // exclusive
    if (tid == 127) offA[(size_t)t * (n + 1) + n] = part[127];
}

// ---------------- phase C: per-chunk scan + carry, write off/cur ----------------
__global__ __launch_bounds__(256) void scanC_k(const int* __restrict__ cntA, const int* __restrict__ boff,
                                               int* __restrict__ offA, int* __restrict__ curA, int n) {
    int b = blockIdx.x;
    int t = b / NCH, ch = b - t * NCH;
    const int* cnt = cntA + (size_t)t * n;
    int* off = offA + (size_t)t * (n + 1);
    int* cur = curA + (size_t)t * n;
    int base = ch * CHSZ;
    int cend = base + CHSZ; if (cend > n) cend = n;
    int s0 = base + threadIdx.x * SPT;
    int e0 = s0 + SPT; if (e0 > cend) e0 = cend;
    int sum = 0;
    for (int i = s0; i < e0 && i < cend; ++i) sum += cnt[i];
    __shared__ int part[256];
    int my = (s0 < cend) ? sum : 0;
    part[threadIdx.x] = my;
    __syncthreads();
    for (int d = 1; d < 256; d <<= 1) {
        int u = (threadIdx.x >= d) ? part[threadIdx.x - d] : 0;
        __syncthreads();
        part[threadIdx.x] += u;
        __syncthreads();
    }
    int excl = boff[t * NCH + ch] + part[threadIdx.x] - my;
    for (int i = s0; i < e0 && i < cend; ++i) {
        off[i] = excl; cur[i] = excl; excl += cnt[i];
    }
}

// ---------------- r_seg partition: per-(block,seg) offsets via wave scan ----------------
__global__ __launch_bounds__(64) void offs3_k(const int* __restrict__ hist, const int* __restrict__ csr,
                                              int* __restrict__ offb) {
    int b = blockIdx.x;            // 0..3*R2-1
    int t = b / R2, s = b - t * R2;
    int lane = threadIdx.x;        // 0..63 = block index
    int v = hist[(size_t)(t * NB + lane) * R2 + s];
    int pre = v;
    for (int o = 1; o < 64; o <<= 1) {
        int u = __shfl_up(pre, o);
        if (lane >= o) pre += u;
    }
    int base = csr[(size_t)t * (R2 + 1) + s];
    offb[(size_t)(t * NB + lane) * R2 + s] = base + pre - v;
}

// ---------------- r_seg partition: scatter with LDS counters ----------------
__global__ __launch_bounds__(256) void part3_k(const int* __restrict__ seg, const int* __restrict__ val,
                                               const int* __restrict__ offb, int* __restrict__ outp) {
    __shared__ int cur[R2];
    int t = blockIdx.x / NB;
    int pb = blockIdx.x - t * NB;
    const int* s = seg + (size_t)t * R2E;
    const int* v = val + (size_t)t * R2E;
    const int* ob = offb + (size_t)(t * NB + pb) * R2;
    int* o = outp + (size_t)t * R2E;
    for (int i = threadIdx.x; i < R2; i += 256) cur[i] = ob[i];
    __syncthreads();
    int beg = pb * RCHUNK;
    int end = beg + RCHUNK; if (end > R2E) end = R2E;
    for (int i = beg + threadIdx.x; i < end; i += 256) {
        int p = atomicAdd(&cur[s[i]], 1);
        o[p] = v[i];
    }
}

// ---------------- batched scatters (entity + super CSR; low contention) ----------------
__global__ void scatter3_k(const int* __restrict__ dst, const int* __restrict__ src,
                           const int* __restrict__ et, int* __restrict__ cur,
                           int* __restrict__ psrc, int* __restrict__ pet,
                           int per_t, int stride, int total) {
    int i = blockIdx.x * 256 + threadIdx.x;
    if (i < total) {
        int t = i / per_t;
        int p = atomicAdd(&cur[t * stride + dst[i]], 1);
        psrc[(size_t)t * per_t + p] = src[i];
        pet[(size_t)t * per_t + p] = et[i];
    }
}

// ---------------- block-aggregated zero-indeg list (1 atomic per block) ----------------
__global__ __launch_bounds__(256) void zlist3b_k(const int* __restrict__ cnt, int* __restrict__ zl,
                                                 int* __restrict__ nz, int n, int bpt) {
    int t = blockIdx.x / bpt;
    int pb = blockIdx.x - t * bpt;
    int i = pb * 256 + threadIdx.x;
    bool z = (i < n) && (cnt[(size_t)t * n + i] == 0);
    unsigned long long mask = __ballot(z);
    int wave = threadIdx.x >> 6, lane = threadIdx.x & 63;
    __shared__ int wbase[4];
    __shared__ int bbase;
    if (lane == 0) wbase[wave] = __popcll(mask);
    __syncthreads();
    if (threadIdx.x == 0) {
        int s0 = wbase[0], s1 = wbase[1], s2 = wbase[2], s3 = wbase[3];
        int tot = s0 + s1 + s2 + s3;
        bbase = tot ? atomicAdd(&nz[t], tot) : 0;
        wbase[0] = 0; wbase[1] = s0; wbase[2] = s0 + s1; wbase[3] = s0 + s1 + s2;
    }
    __syncthreads();
    if (z) {
        int off = bbase + wbase[wave] + __popcll(mask & ((1ull << lane) - 1ull));
        zl[(size_t)t * n + off] = i;
    }
}

// ---------------- small segment sum (SR path), LDS col-chunked ----------------
#define SEG_CW 25
__global__ __launch_bounds__(256) void seg_acc_k(const float* __restrict__ hsrc,
                                                 const int* __restrict__ idx,
                                                 const int* __restrict__ seg, int n,
                                                 float* __restrict__ acc, int nseg) {
    __shared__ float lacc[500 * SEG_CW];
    int cg = blockIdx.x & 7;
    int pb = blockIdx.x >> 3;
    int NPB = gridDim.x >> 3;
    int t = threadIdx.x;
    for (int i = t; i < nseg * SEG_CW; i += 256) lacc[i] = 0.f;
    __syncthreads();
    int chunk = (n + NPB - 1) / NPB;
    int beg = pb * chunk;
    int end = beg + chunk; if (end > n) end = n;
    if (t < 250) {
        int il = t / SEG_CW;
        int c = t - il * SEG_CW;
        int col = cg * SEG_CW + c;
        for (int i = beg + il; i < end; i += 10) {
            int r = seg[i];
            int e = idx[i];
            atomicAdd(&lacc[r * SEG_CW + c], hsrc[(size_t)e * H + col]);
        }
    }
    __syncthreads();
    for (int i = t; i < nseg * SEG_CW; i += 256) {
        int r = i / SEG_CW, c = i - (i / SEG_CW) * SEG_CW;
        atomicAdd(&acc[(size_t)r * H + cg * SEG_CW + c], lacc[i]);
    }
}

// ---------------- seg-mean partials: 4 blocks per segment, disjoint buffers (no atomics) ----------------
__global__ __launch_bounds__(256) void seg_mean_part_k(const u16* __restrict__ h,
                                                       const int* __restrict__ per,
                                                       const int* __restrict__ off,
                                                       float* __restrict__ xpart, int nseg) {
    int r = blockIdx.x >> 2;
    int p = blockIdx.x & 3;
    if (r >= nseg) return;
    int wv = threadIdx.x >> 6, lane = threadIdx.x & 63;
    int beg = off[r], end = off[r + 1];
    float a0 = 0.f, a1 = 0.f, a2 = 0.f, a3 = 0.f;
    for (int i = beg + p * 4 + wv; i < end; i += 16) {
        int e = per[i];
        if (lane < 50) {
            uint2 u = ((const uint2*)(h + (size_t)e * H))[lane];
            a0 += bf2f(u.x & 0xffff); a1 += bf2f(u.x >> 16);
            a2 += bf2f(u.y & 0xffff); a3 += bf2f(u.y >> 16);
        }
    }
    __shared__ float red[4][200];
    if (lane < 50) *(float4*)(&red[wv][lane * 4]) = make_float4(a0, a1, a2, a3);
    __syncthreads();
    int t = threadIdx.x;
    if (t < 200) {
        float s = red[0][t] + red[1][t] + red[2][t] + red[3][t];
        xpart[((size_t)p * nseg + r) * H + t] = s;
    }
}

// ---------------- fused LSTM1: inline seg-mean finalize (xpart sum + divide), t0 cprev in-kernel ----------------
__global__ __launch_bounds__(256) void lstm1f_k(const float* __restrict__ x1,
                                                const float* __restrict__ xpart, const int* __restrict__ off,
                                                const float* __restrict__ hprev, const float* __restrict__ cprevExt,
                                                int t0,
                                                const float* __restrict__ Wih, const float* __restrict__ Whh,
                                                const float* __restrict__ bih, const float* __restrict__ bhh,
                                                float* __restrict__ hout, float* __restrict__ cout, int rows) {
    int r = blockIdx.x;
    if (r >= rows) return;
    __shared__ float xb[2 * H], hb[H], gb[4 * H], hv[H], cv[H];
    __shared__ float red[8];
    int t = threadIdx.x;
    if (t < H) {
        xb[t] = x1[(size_t)r * H + t];
        size_t stride = (size_t)rows * H;
        size_t ix = (size_t)r * H + t;
        float s = xpart[ix] + xpart[stride + ix] + xpart[2 * stride + ix] + xpart[3 * stride + ix];
        int c = off[r + 1] - off[r];
        xb[H + t] = s / (float)(c > 0 ? c : 1);
    }
    if (t < H) hb[t] = hprev[(size_t)r * H + t];
    __syncthreads();
    for (int j = t; j < 4 * H; j += 256) {
        float s = bih[j] + bhh[j];
        const float* wi = Wih + (size_t)j * 2 * H;
        for (int k = 0; k < 2 * H; ++k) s += xb[k] * wi[k];
        const float* wh = Whh + (size_t)j * H;
        for (int k = 0; k < H; ++k) s += hb[k] * wh[k];
        gb[j] = s;
    }
    __syncthreads();
    if (t < H) {
        float cp = t0 ? xb[H + t] : cprevExt[(size_t)r * H + t];
        float ig = fsig(gb[t]);
        float fg = fsig(gb[H + t]);
        float gg = ftanh(gb[2 * H + t]);
        float og = fsig(gb[3 * H + t]);
        float c2 = fg * cp + ig * gg;
        cv[t] = c2;
        hv[t] = og * ftanh(c2);
    }
    __syncthreads();
    float sh = 0.f, sc = 0.f;
    if (t < H) { sh = hv[t] * hv[t]; sc = cv[t] * cv[t]; }
    for (int o = 32; o > 0; o >>= 1) { sh += __shfl_down(sh, o); sc += __shfl_down(sc, o); }
    if ((t & 63) == 0) { red[t >> 6] = sh; red[4 + (t >> 6)] = sc; }
    __syncthreads();
    if (t == 0) {
        red[0] = 1.f / fmaxf(sqrtf(red[0] + red[1] + red[2] + red[3]), 1e-12f);
        red[4] = 1.f / fmaxf(sqrtf(red[4] + red[5] + red[6] + red[7]), 1e-12f);
    }
    __syncthreads();
    if (t < H) {
        hout[(size_t)r * H + t] = hv[t] * red[0];
        cout[(size_t)r * H + t] = cv[t] * red[4];
    }
}

// ---------------- fused LSTM2: inline seg_div (sxacc/cnt), t0 cprev in-kernel ----------------
__global__ __launch_bounds__(256) void lstm2f_k(const float* __restrict__ x1,
                                                const float* __restrict__ sxacc, const int* __restrict__ scnt,
                                                const float* __restrict__ hprev, const float* __restrict__ cprevExt,
                                                int t0,
                                                const float* __restrict__ Wih, const float* __restrict__ Whh,
                                                const float* __restrict__ bih, const float* __restrict__ bhh,
                                                float* __restrict__ hout, float* __restrict__ cout, int rows) {
    int r = blockIdx.x;
    if (r >= rows) return;
    __shared__ float xb[2 * H], hb[H], gb[4 * H], hv[H], cv[H];
    __shared__ float red[8];
    int t = threadIdx.x;
    if (t < H) {
        xb[t] = x1[(size_t)r * H + t];
        int c = scnt[r];
        xb[H + t] = sxacc[(size_t)r * H + t] / (float)(c > 0 ? c : 1);
        hb[t] = hprev[(size_t)r * H + t];
    }
    __syncthreads();
    for (int j = t; j < 4 * H; j += 256) {
        float s = bih[j] + bhh[j];
        const float* wi = Wih + (size_t)j * 2 * H;
        for (int k = 0; k < 2 * H; ++k) s += xb[k] * wi[k];
        const float* wh = Whh + (size_t)j * H;
        for (int k = 0; k < H; ++k) s += hb[k] * wh[k];
        gb[j] = s;
    }
    __syncthreads();
    if (t < H) {
        float cp = t0 ? xb[H + t] : cprevExt[(size_t)r * H + t];
        float ig = fsig(gb[t]);
        float fg = fsig(gb[H + t]);
        float gg = ftanh(gb[2 * H + t]);
        float og = fsig(gb[3 * H + t]);
        float c2 = fg * cp + ig * gg;
        cv[t] = c2;
        hv[t] = og * ftanh(c2);
    }
    __syncthreads();
    float sh = 0.f, sc = 0.f;
    if (t < H) { sh = hv[t] * hv[t]; sc = cv[t] * cv[t]; }
    for (int o = 32; o > 0; o >>= 1) { sh += __shfl_down(sh, o); sc += __shfl_down(sc, o); }
    if ((t & 63) == 0) { red[t >> 6] = sh; red[4 + (t >> 6)] = sc; }
    __syncthreads();
    if (t == 0) {
        red[0] = 1.f / fmaxf(sqrtf(red[0] + red[1] + red[2] + red[3]), 1e-12f);
        red[4] = 1.f / fmaxf(sqrtf(red[4] + red[5] + red[6] + red[7]), 1e-12f);
    }
    __syncthreads();
    if (t < H) {
        hout[(size_t)r * H + t] = hv[t] * red[0];
        cout[(size_t)r * H + t] = cv[t] * red[4];
    }
}

// ---------------- fused small GRU: inline l2norm of x, + l2norm of out (+bf16 mirror) ----------------
__global__ __launch_bounds__(256) void gru_smallf_k(const float* __restrict__ x, const float* __restrict__ h,
                                                    const float* __restrict__ Wih, const float* __restrict__ Whh,
                                                    const float* __restrict__ bih, const float* __restrict__ bhh,
                                                    float* __restrict__ outp, u16* __restrict__ mirp, int rows) {
    int r = blockIdx.x;
    if (r >= rows) return;
    __shared__ float xb[H], hb[H], gi[3 * H], gh[3 * H], ov[H];
    __shared__ float red[4];
    int t = threadIdx.x;
    float xv = 0.f;
    if (t < H) { xv = x[(size_t)r * H + t]; hb[t] = h[(size_t)r * H + t]; }
    // normalize x row first
    float sx = xv * xv;
    for (int o = 32; o > 0; o >>= 1) sx += __shfl_down(sx, o);
    if ((t & 63) == 0) red[t >> 6] = sx;
    __syncthreads();
    if (t == 0) red[0] = 1.f / fmaxf(sqrtf(red[0] + red[1] + red[2] + red[3]), 1e-12f);
    __syncthreads();
    if (t < H) xb[t] = xv * red[0];
    __syncthreads();
    for (int j = t; j < 3 * H; j += 256) {
        float si = bih[j], sh2 = bhh[j];
        const float* wi = Wih + (size_t)j * H;
        const float* wh = Whh + (size_t)j * H;
        for (int k = 0; k < H; ++k) { si += xb[k] * wi[k]; sh2 += hb[k] * wh[k]; }
        gi[j] = si; gh[j] = sh2;
    }
    __syncthreads();
    if (t < H) {
        float rr = fsig(gi[t] + gh[t]);
        float zz = fsig(gi[H + t] + gh[H + t]);
        float nn = ftanh(gi[2 * H + t] + rr * gh[2 * H + t]);
        ov[t] = (1.f - zz) * nn + zz * hb[t];
    }
    __syncthreads();
    float s = (t < H) ? ov[t] * ov[t] : 0.f;
    for (int o = 32; o > 0; o >>= 1) s += __shfl_down(s, o);
    if ((t & 63) == 0) red[t >> 6] = s;
    __syncthreads();
    if (t == 0) red[0] = 1.f / fmaxf(sqrtf(red[0] + red[1] + red[2] + red[3]), 1e-12f);
    __syncthreads();
    if (t < H) {
        float v = ov[t] * red[0];
        outp[(size_t)r * H + t] = v;
        mirp[(size_t)r * H + t] = f2bf(v);
    }
}

// ---------------- fused super-graph layer: gather + rrelu(agg@Wn + cur@Wsel) ----------------
__global__ __launch_bounds__(256) void sup_fused_k(const float* __restrict__ cur, const float* __restrict__ prel,
                                                   const int* __restrict__ soff, const int* __restrict__ sssrc,
                                                   const int* __restrict__ sset,
                                                   const float* __restrict__ Wn, const float* __restrict__ We,
                                                   const float* __restrict__ Wl, const int* __restrict__ indeg,
                                                   float* __restrict__ outp) {
    int r = blockIdx.x;
    __shared__ float ar[H], cr[H];
    int t = threadIdx.x;
    if (t < H) {
        int beg = soff[r], end = soff[r + 1];
        float acc = 0.f;
        for (int i = beg; i < end; ++i)
            acc += cur[(size_t)sssrc[i] * H + t] + prel[(size_t)sset[i] * H + t];
        ar[t] = acc;
        cr[t] = cur[(size_t)r * H + t];
    }
    __syncthreads();
    const float* W2 = (indeg[r] > 0) ? We : Wl;
    if (t < H) {
        float s = 0.f;
        for (int k = 0; k < H; ++k) s += ar[k] * Wn[(size_t)k * H + t] + cr[k] * W2[(size_t)k * H + t];
        outp[(size_t)r * H + t] = (s >= 0.f) ? s : s * SLOPE;
    }
}

// ---------------- entity message aggregation via CSR (wave per dst), 2-edge unrolled ----------------
__global__ __launch_bounds__(256) void ent_agg_b_k(const u16* __restrict__ cur, const u16* __restrict__ rel,
                                                   const int* __restrict__ eoff, const int* __restrict__ esrc,
                                                   const int* __restrict__ eet, u16* __restrict__ agg, int n) {
    int wave = threadIdx.x >> 6, lane = threadIdx.x & 63;
    int v = blockIdx.x * 4 + wave;
    if (v >= n) return;
    float a0 = 0.f, a1 = 0.f, a2 = 0.f, a3 = 0.f;
    bool act = lane < 50;
    int beg = eoff[v], end = eoff[v + 1];
    int i = beg;
    for (; i + 2 <= end; i += 2) {
        int e0 = esrc[i], t0 = eet[i];
        int e1 = esrc[i + 1], t1 = eet[i + 1];
        if (act) {
            uint2 h0 = ((const uint2*)(cur + (size_t)e0 * H))[lane];
            uint2 h1 = ((const uint2*)(cur + (size_t)e1 * H))[lane];
            uint2 r0 = ((const uint2*)(rel + (size_t)t0 * H))[lane];
            uint2 r1 = ((const uint2*)(rel + (size_t)t1 * H))[lane];
            a0 += bf2f(h0.x & 0xffff) + bf2f(r0.x & 0xffff) + bf2f(h1.x & 0xffff) + bf2f(r1.x & 0xffff);
            a1 += bf2f(h0.x >> 16) + bf2f(r0.x >> 16) + bf2f(h1.x >> 16) + bf2f(r1.x >> 16);
            a2 += bf2f(h0.y & 0xffff) + bf2f(r0.y & 0xffff) + bf2f(h1.y & 0xffff) + bf2f(r1.y & 0xffff);
            a3 += bf2f(h0.y >> 16) + bf2f(r0.y >> 16) + bf2f(h1.y >> 16) + bf2f(r1.y >> 16);
        }
    }
    if (i < end) {
        int e0 = esrc[i], t0 = eet[i];
        if (act) {
            uint2 h0 = ((const uint2*)(cur + (size_t)e0 * H))[lane];
            uint2 r0 = ((const uint2*)(rel + (size_t)t0 * H))[lane];
            a0 += bf2f(h0.x & 0xffff) + bf2f(r0.x & 0xffff);
            a1 += bf2f(h0.x >> 16) + bf2f(r0.x >> 16);
            a2 += bf2f(h0.y & 0xffff) + bf2f(r0.y & 0xffff);
            a3 += bf2f(h0.y >> 16) + bf2f(r0.y >> 16);
        }
    }
    if (act) {
        uint2 o; o.x = pk2(a0, a1); o.y = pk2(a2, a3);
        ((uint2*)(agg + (size_t)v * H))[lane] = o;
    }
}

// ---------------- B-persistent bf16 MFMA GEMM, split-k B staging + partial last col group ----------------
#define BSTR 108   // padded LDS row stride
__global__ __launch_bounds__(128) void gemm_bp_k(const u16* __restrict__ A1, const u16* __restrict__ A2,
                                                 const u16* __restrict__ B1, const u16* __restrict__ B2,
                                                 u16* __restrict__ Cm, int M, int Nc) {
    __shared__ __bf16 Bs[64 * BSTR];  // 13824 B
    const int tid = threadIdx.x;
    int idx2 = xcd_swz(blockIdx.x, gridDim.x);
    const int m0 = (idx2 >> 2) * 128;
    const int n0 = (idx2 & 3) * 64;
    const int nfb = (n0 + 16 >= Nc) ? 1 : 4;        // last col group: only 1 useful 16-col frag
    const int brows = (nfb == 1) ? 16 : 64;
    const int w = tid >> 6, lane = tid & 63;
    const int lr = lane & 15, lo = lane >> 4;
    const int mbase = m0 + w * 64;

    bf8 zb;
#pragma unroll
    for (int e = 0; e < 8; ++e) zb[e] = (__bf16)0.f;

    f32x4 acc[4][4];
#pragma unroll
    for (int i = 0; i < 4; ++i)
#pragma unroll
        for (int j = 0; j < 4; ++j)
#pragma unroll
            for (int e = 0; e < 4; ++e) acc[i][j][e] = 0.f;

    auto stageB = [&](const u16* Bp, int kbase, int nch) {
        for (int ch = tid; ch < brows * nch; ch += 128) {
            int n = ch / nch, q = ch - n * nch;
            int ng = n0 + n;
            uint4 v = make_uint4(0, 0, 0, 0);
            if (ng < Nc) v = *(const uint4*)(Bp + (size_t)ng * 200 + kbase + q * 8);
            *(uint4*)(&Bs[n * BSTR + q * 8]) = v;
        }
    };
    auto loadA = [&](bf8* buf, const u16* Ap, int kt7) {
        int kk = kt7 * 32 + lo * 8;
        bool kv = kk < 200;
#pragma unroll
        for (int mf = 0; mf < 4; ++mf) {
            int m = mbase + mf * 16 + lr;
            bf8 v = zb;
            if (kv && m < M) v = *(const bf8*)(Ap + (size_t)m * 200 + kk);
            buf[mf] = v;
        }
    };
    auto mmaStep = [&](bf8* a, int kt7, int kbase) {
        int kk = kt7 * 32 + lo * 8;
        int kcl = (kk < 200) ? (kk - kbase) : 0;
#pragma unroll
        for (int nf = 0; nf < 4; ++nf) {
            if (nf < nfb) {
                bf8 b = *(const bf8*)(&Bs[(nf * 16 + lr) * BSTR + kcl]);
#pragma unroll
                for (int mf = 0; mf < 4; ++mf)
                    acc[mf][nf] = __builtin_amdgcn_mfma_f32_16x16x32_bf16(a[mf], b, acc[mf][nf], 0, 0, 0);
            }
        }
    };

    bf8 a0[4], a1[4];
    stageB(B1, 0, 12);
    __syncthreads();
    loadA(a0, A1, 0);
    loadA(a1, A1, 1); mmaStep(a0, 0, 0);
    loadA(a0, A1, 2); mmaStep(a1, 1, 0);
    loadA(a1, A1, 3); mmaStep(a0, 2, 0);
    __syncthreads();
    stageB(B1, 96, 13);
    __syncthreads();
    loadA(a0, A1, 4); mmaStep(a1, 3, 96);
    loadA(a1, A1, 5); mmaStep(a0, 4, 96);
    loadA(a0, A1, 6); mmaStep(a1, 5, 96);
    loadA(a1, A2, 0); mmaStep(a0, 6, 96);
    __syncthreads();
    stageB(B2, 0, 12);
    __syncthreads();
    loadA(a0, A2, 1); mmaStep(a1, 0, 0);
    loadA(a1, A2, 2); mmaStep(a0, 1, 0);
    loadA(a0, A2, 3); mmaStep(a1, 2, 0);
    __syncthreads();
    stageB(B2, 96, 13);
    __syncthreads();
    loadA(a1, A2, 4); mmaStep(a0, 3, 96);
    loadA(a0, A2, 5); mmaStep(a1, 4, 96);
    loadA(a1, A2, 6); mmaStep(a0, 5, 96);
    mmaStep(a1, 6, 96);

#pragma unroll
    for (int mf = 0; mf < 4; ++mf) {
#pragma unroll
        for (int r = 0; r < 4; ++r) {
            int m = mbase + mf * 16 + lo * 4 + r;
            if (m >= M) continue;
#pragma unroll
            for (int nf = 0; nf < 4; ++nf) {
                if (nf >= nfb) continue;
                int n = n0 + nf * 16 + lr;
                if (n >= Nc) continue;
                float v = acc[mf][nf][r];
                v = (v >= 0.f) ? v : v * SLOPE;
                Cm[(size_t)m * Nc + n] = f2bf(v);
            }
        }
    }
}

// ---------------- fixup for zero-indeg rows: out[row] = rrelu(h[row] @ Wl), bf16 io ----------------
__global__ __launch_bounds__(256) void fixup_b_k(const u16* __restrict__ h, const float* __restrict__ Wl,
                                                 const int* __restrict__ zl, const int* __restrict__ nz,
                                                 u16* __restrict__ outp) {
    __shared__ float xr[H];
    int nzv = *nz;
    for (int z = blockIdx.x; z < nzv; z += gridDim.x) {
        int row = zl[z];
        if (threadIdx.x < H) xr[threadIdx.x] = bf2f(h[(size_t)row * H + threadIdx.x]);
        __syncthreads();
        if (threadIdx.x < H) {
            float s = 0.f;
            for (int k = 0; k < H; ++k) s += xr[k] * Wl[(size_t)k * H + threadIdx.x];
            outp[(size_t)row * H + threadIdx.x] = f2bf((s >= 0.f) ? s : s * SLOPE);
        }
        __syncthreads();
    }
}

// ---------------- W-in-LDS entity GRU: padded LDS (204), bf16 h for z*h, bf16 out ----------------
#define GCG2 13       // col groups of 16
#define GTPB 6        // row tiles (128 rows each) per block
#define WSTR 204      // padded Ws row stride
__global__ __launch_bounds__(256, 4) void gru_wlds_k(const u16* __restrict__ Xb, const u16* __restrict__ Hb,
                                                     const u16* __restrict__ Wb,
                                                     const float* __restrict__ bih, const float* __restrict__ bhh,
                                                     u16* __restrict__ Outb, int M) {
    __shared__ __bf16 Ws[6][16 * WSTR];   // 39168 B
    const int tid = threadIdx.x;
    int idx2 = xcd_swz(blockIdx.x, gridDim.x);
    const int cg = idx2 % GCG2;
    const int rb = idx2 / GCG2;
    const int w = tid >> 6, lane = tid & 63;
    const int lr = lane & 15, lo = lane >> 4;
    const int c0 = cg * 16;

    for (int ch = tid; ch < 2400; ch += 256) {
        int s = ch / 400;
        int rem = ch - s * 400;
        int col = rem / 25, q = rem - (rem / 25) * 25;
        int cc = c0 + col; if (cc > 199) cc = 199;
        uint4 v = *(const uint4*)(Wb + (size_t)(s * 200 + cc) * 200 + q * 8);
        *(uint4*)(&Ws[s][col * WSTR + q * 8]) = v;
    }
    __syncthreads();

    int c = c0 + lr;
    const bool cvalid = c < 200;
    const int cc = cvalid ? c : 199;
    const float b0 = bih[cc], b1 = bih[200 + cc], b2 = bih[400 + cc];
    const float b3 = bhh[cc], b4 = bhh[200 + cc], b5 = bhh[400 + cc];

    bf8 zb;
#pragma unroll
    for (int e = 0; e < 8; ++e) zb[e] = (__bf16)0.f;

    for (int tile = 0; tile < GTPB; ++tile) {
        int mbase = (rb * GTPB + tile) * 128 + w * 32;
        if (mbase >= M) break;
        int m0r = mbase + lr;      if (m0r >= M) m0r = M - 1;
        int m1r = mbase + 16 + lr; if (m1r >= M) m1r = M - 1;
        const u16* Xp0 = Xb + (size_t)m0r * 200 + lo * 8;
        const u16* Xp1 = Xb + (size_t)m1r * 200 + lo * 8;
        const u16* Hp0 = Hb + (size_t)m0r * 200 + lo * 8;
        const u16* Hp1 = Hb + (size_t)m1r * 200 + lo * 8;

        f32x4 acc[6][2];
#pragma unroll
        for (int s = 0; s < 6; ++s)
#pragma unroll
            for (int i = 0; i < 2; ++i)
#pragma unroll
                for (int e = 0; e < 4; ++e) acc[s][i][e] = 0.f;

#pragma unroll
        for (int kt = 0; kt < 7; ++kt) {
            const int koff = kt * 32;
            const bool kv = (kt < 6) || (lo == 0);
            const int kcl = kv ? (koff + lo * 8) : 0;
            bf8 xa0 = zb, xa1 = zb, ha0 = zb, ha1 = zb;
            if (kv) {
                xa0 = *(const bf8*)(Xp0 + koff);
                xa1 = *(const bf8*)(Xp1 + koff);
                ha0 = *(const bf8*)(Hp0 + koff);
                ha1 = *(const bf8*)(Hp1 + koff);
            }
#pragma unroll
            for (int s = 0; s < 6; ++s) {
                bf8 wv = *(const bf8*)(&Ws[s][lr * WSTR + kcl]);
                bf8 a0f = (s < 3) ? xa0 : ha0;
                bf8 a1f = (s < 3) ? xa1 : ha1;
                acc[s][0] = __builtin_amdgcn_mfma_f32_16x16x32_bf16(a0f, wv, acc[s][0], 0, 0, 0);
                acc[s][1] = __builtin_amdgcn_mfma_f32_16x16x32_bf16(a1f, wv, acc[s][1], 0, 0, 0);
            }
        }
        if (cvalid) {
#pragma unroll
            for (int mf = 0; mf < 2; ++mf) {
#pragma unroll
                for (int r = 0; r < 4; ++r) {
                    int m = mbase + mf * 16 + lo * 4 + r;
                    if (m >= M) continue;
                    float ir = acc[0][mf][r] + b0;
                    float iz = acc[1][mf][r] + b1;
                    float in_ = acc[2][mf][r] + b2;
                    float hr = acc[3][mf][r] + b3;
                    float hz = acc[4][mf][r] + b4;
                    float hn = acc[5][mf][r] + b5;
                    float rr = fsig(ir + hr);
                    float zz = fsig(iz + hz);
                    float nn = ftanh(in_ + rr * hn);
                    float hvv = bf2f(Hb[(size_t)m * 200 + c]);
                    Outb[(size_t)m * 200 + c] = f2bf((1.f - zz) * nn + zz * hvv);
                }
            }
        }
    }
}

// =========================== host orchestration ===========================
extern "C" void kernel_launch(void* const* d_in, const int* in_sizes, int n_in,
                              void* d_out, int out_size, void* d_ws, size_t ws_size,
                              hipStream_t stream) {
    (void)in_sizes; (void)n_in; (void)out_size; (void)ws_size;
    const int* src  = (const int*)d_in[0];
    const int* dst  = (const int*)d_in[1];
    const int* etyp = (const int*)d_in[2];
    const int* rte  = (const int*)d_in[3];
    const int* rseg = (const int*)d_in[4];
    const int* ssrc = (const int*)d_in[5];
    const int* sdst = (const int*)d_in[6];
    const int* setp = (const int*)d_in[7];
    const int* srte = (const int*)d_in[8];
    const int* srseg= (const int*)d_in[9];
    const float* dyn     = (const float*)d_in[10];
    const float* emb_rel = (const float*)d_in[11];
    const float* p_rel   = (const float*)d_in[12];
    const float* Wih1 = (const float*)d_in[13]; const float* Whh1 = (const float*)d_in[14];
    const float* bih1 = (const float*)d_in[15]; const float* bhh1 = (const float*)d_in[16];
    const float* Wih2 = (const float*)d_in[17]; const float* Whh2 = (const float*)d_in[18];
    const float* bih2 = (const float*)d_in[19]; const float* bhh2 = (const float*)d_in[20];
    const float* Wih3 = (const float*)d_in[21]; const float* Whh3 = (const float*)d_in[22];
    const float* bih3 = (const float*)d_in[23]; const float* bhh3 = (const float*)d_in[24];
    const float* Wihe = (const float*)d_in[25]; const float* Whhe = (const float*)d_in[26];
    const float* bihe = (const float*)d_in[27]; const float* bhhe = (const float*)d_in[28];
    const float* Wn  = (const float*)d_in[29];
    const float* Wl  = (const float*)d_in[30];
    const float* We  = (const float*)d_in[31];
    const float* sWn = (const float*)d_in[32];
    const float* sWl = (const float*)d_in[33];
    const float* sWe = (const float*)d_in[34];

    float* out = (float*)d_out;
    const size_t NH = (size_t)N_NODES * H;
    float* relout = out + 3 * NH;

    char* wp = (char*)d_ws;
    auto carve = [&](size_t bytes) -> void* {
        void* p = (void*)wp;
        wp += (bytes + 255) & ~(size_t)255;
        return p;
    };
    u16* aggB = (u16*)carve(NH * 2);
    u16* m0b  = (u16*)carve(NH * 2);
    u16* m1b  = (u16*)carve(NH * 2);
    u16* hmir = (u16*)carve(NH * 2);
    u16* gob  = (u16*)carve(NH * 2);   // bf16 GRU output
    u16* relm = (u16*)carve((size_t)R2 * H * 2);
    u16* wtB  = (u16*)carve((size_t)400000 * 2);
    float* h0a  = (float*)carve((size_t)R2 * H * 4);
    float* c0b  = (float*)carve((size_t)R2 * H * 4);
    float* xpart= (float*)carve((size_t)4 * R2 * H * 4);
    float* srelA= (float*)carve((size_t)R2 * H * 4);
    float* srelB= (float*)carve((size_t)R2 * H * 4);
    float* sxin = (float*)carve((size_t)SR * H * 4);
    float* p_h  = (float*)carve((size_t)SR * H * 4);
    float* p_c  = (float*)carve((size_t)SR * H * 4);
    // persistent (used inside t-loop) batched CSR data
    int* eoff3  = (int*)carve((size_t)3 * (N_NODES + 1) * 4);
    int* esrcp3 = (int*)carve((size_t)3 * E_EDGES * 4);
    int* eetp3  = (int*)carve((size_t)3 * E_EDGES * 4);
    int* zl3    = (int*)carve((size_t)3 * N_NODES * 4);
    int* nz3    = (int*)carve(3 * 4);
    int* rcsr3  = (int*)carve((size_t)3 * (R2 + 1) * 4);
    int* rper3  = (int*)carve((size_t)3 * R2E * 4);
    int* sindeg3= (int*)carve((size_t)3 * R2 * 4);
    int* scnt3  = (int*)carve((size_t)3 * SR * 4);
    int* hist3  = (int*)carve((size_t)3 * NB * R2 * 4);
    int* offb3  = (int*)carve((size_t)3 * NB * R2 * 4);
    int* soff3  = (int*)carve((size_t)3 * (R2 + 1) * 4);
    int* scur3  = (int*)carve((size_t)3 * R2 * 4);
    int* sssrc3 = (int*)carve((size_t)3 * SE_EDGES * 4);
    int* sset3  = (int*)carve((size_t)3 * SE_EDGES * 4);
    int* bsum3  = (int*)carve((size_t)3 * NCH * 4);
    int* boff3  = (int*)carve((size_t)3 * NCH * 4);
    // transient (pre-loop only) arrays aliased into loop-phase buffers
    int* ecnt3 = (int*)m0b;
    int* rcnt3 = (int*)m0b + 3 * N_NODES;
    int* ecur3 = (int*)aggB;
    int* rcur3 = (int*)aggB + 3 * N_NODES;

    // ---- weights -> bf16 ----
    dim3 wg4(157, 4);
    wconv4_k<<<wg4, 256, 0, stream>>>(Wn, We, Wn + 40000, We + 40000, wtB);
    wconv2_k<<<938, 256, 0, stream>>>(Wihe, Whhe, wtB + 160000);

    // ---- batched graph preprocessing ----
    hipMemsetAsync(ecnt3, 0, (size_t)3 * N_NODES * 4, stream);
    hipMemsetAsync(rcnt3, 0, (size_t)3 * R2 * 4, stream);
    hipMemsetAsync(nz3, 0, 3 * 4, stream);
    hipMemsetAsync(sindeg3, 0, (size_t)3 * R2 * 4, stream);
    hipMemsetAsync(scnt3, 0, (size_t)3 * SR * 4, stream);
    cnt3_k<<<(3 * E_EDGES + 255) / 256, 256, 0, stream>>>(dst, 3 * E_EDGES, E_EDGES, N_NODES, ecnt3);
    scanA_k<<<3 * NCH, 256, 0, stream>>>(ecnt3, bsum3, N_NODES);
    scanB_k<<<3, 128, 0, stream>>>(bsum3, boff3, eoff3, N_NODES);
    scanC_k<<<3 * NCH, 256, 0, stream>>>(ecnt3, boff3, eoff3, ecur3, N_NODES);
    scatter3_k<<<(3 * E_EDGES + 255) / 256, 256, 0, stream>>>(dst, src, etyp, ecur3, esrcp3, eetp3,
                                                             E_EDGES, N_NODES, 3 * E_EDGES);
    {
        int bpt = (N_NODES + 255) / 256;
        zlist3b_k<<<3 * bpt, 256, 0, stream>>>(ecnt3, zl3, nz3, N_NODES, bpt);
    }
    hist3_k<<<3 * NB, 256, 0, stream>>>(rseg, hist3, rcnt3);
    scan3_k<<<3, 1024, 0, stream>>>(rcnt3, rcsr3, rcur3, R2);
    offs3_k<<<3 * R2, 64, 0, stream>>>(hist3, rcsr3, offb3);
    part3_k<<<3 * NB, 256, 0, stream>>>(rseg, rte, offb3, rper3);
    seg_cnt3_k<<<12, 256, 0, stream>>>(srseg, S2E, SR, 4, scnt3);
    cnt3_k<<<(3 * SE_EDGES + 255) / 256, 256, 0, stream>>>(sdst, 3 * SE_EDGES, SE_EDGES, R2, sindeg3);
    scan3_k<<<3, 1024, 0, stream>>>(sindeg3, soff3, scur3, R2);
    scatter3_k<<<(3 * SE_EDGES + 255) / 256, 256, 0, stream>>>(sdst, ssrc, setp, scur3, sssrc3, sset3,
                                                              SE_EDGES, R2, 3 * SE_EDGES);

    // h = l2norm(dynamic_emb) -> out+NH (scratch fp32) + hmir
    l2norm_k<<<(N_NODES + 3) / 4, 256, 0, stream>>>(dyn, out + NH, hmir, N_NODES);

    const int gw  = 4 * ((N_NODES + 127) / 128);                       // 3128 blocks of 128 thr
    const int NRB2 = (N_NODES + GTPB * 128 - 1) / (GTPB * 128);        // 131
    const int gwg = GCG2 * NRB2;                                       // 1703 blocks of 256 thr

    for (int t = 0; t < T_STEPS; ++t) {
        const int* srte_t = srte + (size_t)t * S2E;
        const int* srseg_t= srseg + (size_t)t * S2E;
        const int* eoff_t = eoff3 + (size_t)t * (N_NODES + 1);
        const int* esrc_t = esrcp3 + (size_t)t * E_EDGES;
        const int* eet_t  = eetp3 + (size_t)t * E_EDGES;
        const int* zl_t   = zl3 + (size_t)t * N_NODES;
        const int* nz_t   = nz3 + t;
        const int* rcsr_t = rcsr3 + (size_t)t * (R2 + 1);
        const int* rper_t = rper3 + (size_t)t * R2E;
        const int* sind_t = sindeg3 + (size_t)t * R2;
        const int* scnt_t = scnt3 + (size_t)t * SR;
        const int* soff_t = soff3 + (size_t)t * (R2 + 1);
        const int* sssrc_t= sssrc3 + (size_t)t * SE_EDGES;
        const int* sset_t = sset3 + (size_t)t * SE_EDGES;

        float* hist = out + (size_t)t * NH;
        float* rel_t = relout + (size_t)t * R2 * H;
        const float* hprev = (t == 0) ? emb_rel : relout + (size_t)(t - 1) * R2 * H;
        const float* php   = (t == 0) ? p_rel : p_h;

        // ---- x_input partials + fused LSTM1 (seg_fin folded in) ----
        seg_mean_part_k<<<R2 * 4, 256, 0, stream>>>(hmir, rper_t, rcsr_t, xpart, R2);
        lstm1f_k<<<R2, 256, 0, stream>>>(emb_rel, xpart, rcsr_t, hprev, c0b, (t == 0) ? 1 : 0,
                                         Wih1, Whh1, bih1, bhh1, h0a, c0b, R2);
        // ---- sx accumulate + fused LSTM2 (seg_div folded in) ----
        hipMemsetAsync(sxin, 0, (size_t)SR * H * 4, stream);
        seg_acc_k<<<16 * 8, 256, 0, stream>>>(h0a, srte_t, srseg_t, S2E, sxin, SR);
        lstm2f_k<<<SR, 256, 0, stream>>>(p_rel, sxin, scnt_t, php, p_c, (t == 0) ? 1 : 0,
                                         Wih2, Whh2, bih2, bhh2, p_h, p_c, SR);
        // ---- super RGCN (2 fused layers) ----
        sup_fused_k<<<R2, 256, 0, stream>>>(h0a, p_h, soff_t, sssrc_t, sset_t, sWn, sWe, sWl, sind_t, srelA);
        sup_fused_k<<<R2, 256, 0, stream>>>(srelA, p_h, soff_t, sssrc_t, sset_t,
                                            sWn + H * H, sWe + H * H, sWl + H * H, sind_t, srelB);
        // ---- rel GRU (x l2norm folded in) -> rel_embs[t] (+bf16 mirror) ----
        gru_smallf_k<<<R2, 256, 0, stream>>>(srelB, h0a, Wih3, Whh3, bih3, bhh3, rel_t, relm, R2);

        // ---- entity layer 0 (bf16 in, bf16 out) ----
        ent_agg_b_k<<<(N_NODES + 3) / 4, 256, 0, stream>>>(hmir, relm, eoff_t, esrc_t, eet_t, aggB, N_NODES);
        gemm_bp_k<<<gw, 128, 0, stream>>>(aggB, hmir, wtB, wtB + 40000, m0b, N_NODES, H);
        fixup_b_k<<<2048, 256, 0, stream>>>(hmir, Wl, zl_t, nz_t, m0b);
        // ---- entity layer 1 ----
        ent_agg_b_k<<<(N_NODES + 3) / 4, 256, 0, stream>>>(m0b, relm, eoff_t, esrc_t, eet_t, aggB, N_NODES);
        gemm_bp_k<<<gw, 128, 0, stream>>>(aggB, m0b, wtB + 80000, wtB + 120000, m1b, N_NODES, H);
        fixup_b_k<<<2048, 256, 0, stream>>>(m0b, Wl + H * H, zl_t, nz_t, m1b);
        l2norm_b_k<<<(N_NODES + 3) / 4, 256, 0, stream>>>(m1b, N_NODES);

        // ---- W-in-LDS entity GRU (bf16 out) -> l2norm to fp32 hist + hmir ----
        gru_wlds_k<<<gwg, 256, 0, stream>>>(m1b, hmir, wtB + 160000, bihe, bhhe, gob, N_NODES);
        l2norm_bb_k<<<(N_NODES + 3) / 4, 256, 0, stream>>>(gob, hist, hmir, N_NODES);
    }
}